// Round 12
// baseline (336.671 us; speedup 1.0000x reference)
//
#include <hip/hip_runtime.h>

#define NE 64
#define TAU 1e-4f  // 4-term split-bf16 score sigma ~5e-6 -> 20-sigma guard
#define LSTR 68    // 68 mod 32 = 4 -> 2-way (free) LDS access in epilogue

typedef __bf16 bf16x8 __attribute__((ext_vector_type(8)));
typedef float f32x4 __attribute__((ext_vector_type(4)));

// split f32 -> bf16 hi + bf16 lo (hi RNE, lo = RNE(x - hi); x-hi exact in f32)
__device__ __forceinline__ void split8(const float4 a0, const float4 a1,
                                       bf16x8& hi, bf16x8& lo) {
  const float xs[8] = {a0.x, a0.y, a0.z, a0.w, a1.x, a1.y, a1.z, a1.w};
#pragma unroll
  for (int i = 0; i < 8; ++i) {
    const __bf16 h = (__bf16)xs[i];
    hi[i] = h;
    lo[i] = (__bf16)(xs[i] - (float)h);
  }
}

// ---- Kernel Z: zero cnt+hist ------------------------------------------------
__global__ void zero512(int* __restrict__ p) { p[threadIdx.x] = 0; }

// ---- Kernel 0: W -> bf16 hi/lo in FRAGMENT-MAJOR 32-k tiles (1 MB, once) ---
// elem(tt, j, lk, lr, kr) = tt*2048 + j*512 + (lk*16+lr)*8 + kr
// where W-row e = 16j+lr, k = 32tt + 8lk + kr. A wave's B-fragment load is
// 64 lanes x 16B contiguous (1 KB) -> perfectly coalesced, L2-resident.
__global__ __launch_bounds__(256) void wconvert(const float* __restrict__ W,
                                                __bf16* __restrict__ Whi,
                                                __bf16* __restrict__ Wlo,
                                                int n8, int H) {
  const int i = blockIdx.x * 256 + threadIdx.x;
  if (i >= n8) return;
  const int hc = H >> 3;
  const int e = i / hc;
  const int k0 = (i - e * hc) * 8;
  const float4 a0 = *reinterpret_cast<const float4*>(W + (size_t)e * H + k0);
  const float4 a1 =
      *reinterpret_cast<const float4*>(W + (size_t)e * H + k0 + 4);
  bf16x8 hi, lo;
  split8(a0, a1, hi, lo);
  const int tt = k0 >> 5, lk = (k0 >> 3) & 3, j = e >> 4, lr = e & 15;
  const size_t off = (size_t)tt * 2048 + j * 512 + (lk * 16 + lr) * 8;
  *reinterpret_cast<bf16x8*>(Whi + off) = hi;
  *reinterpret_cast<bf16x8*>(Wlo + off) = lo;
}

// ------- Kernel 1: register-pipelined split-bf16 MFMA GEMM ------------------
// NO LDS / NO barriers / NO asm waitcnt in the main loop. Block = 4 waves,
// 32 tokens: wave = (kh, tg); tg picks token group [16tg,16tg+16), kh picks
// k-half. grid N/32 = 1024 -> 4 blocks/CU -> 4 waves/SIMD of TLP.
// Per 32-k iter per wave: issue 10 VMEM for t+1 (2 A float4 + 8 B bf16x8),
// sched_barrier(0) pins them BEFORE the 16 MFMA of tile t; compiler emits
// counted vmcnt at first use -> 1-tile-deep pipeline per wave, x16 waves/CU.
__global__ __launch_bounds__(256, 4) void gemm_fused(
    const float* __restrict__ X, const __bf16* __restrict__ Whi,
    const __bf16* __restrict__ Wlo, const float* __restrict__ bias,
    float* __restrict__ S, float* __restrict__ wout, float* __restrict__ iout,
    int* __restrict__ cnt, int* __restrict__ hist, int* __restrict__ list,
    int cap, int H, int K) {
  __shared__ float Ls[32 * LSTR];  // 8.7 KB: partial-sum + transpose buffer
  __shared__ int hist_s[NE];
  const int tid = threadIdx.x;
  const int lane = tid & 63;
  const int wave = tid >> 6;
  const int tg = wave & 1;   // token group
  const int kh = wave >> 1;  // k half
  if (tid < NE) hist_s[tid] = 0;
  const int lr = lane & 15;
  const int lk = lane >> 4;
  const int row0 = blockIdx.x * 32;
  const int ITERS = H / 64;  // 32-k tiles per k-half (64)

  const float* xp =
      X + (size_t)(row0 + 16 * tg + lr) * H + kh * (H / 2) + 8 * lk;
  const __bf16* bh = Whi + (size_t)(kh * ITERS) * 2048 + (lk * 16 + lr) * 8;
  const __bf16* bl = Wlo + (size_t)(kh * ITERS) * 2048 + (lk * 16 + lr) * 8;

  f32x4 acc[4] = {};

  // prologue: tile 0 into 'cur'
  float4 a0c = *reinterpret_cast<const float4*>(xp);
  float4 a1c = *reinterpret_cast<const float4*>(xp + 4);
  bf16x8 BHc[4], BLc[4];
#pragma unroll
  for (int j = 0; j < 4; ++j) {
    BHc[j] = *reinterpret_cast<const bf16x8*>(bh + j * 512);
    BLc[j] = *reinterpret_cast<const bf16x8*>(bl + j * 512);
  }

  for (int t = 0; t < ITERS; ++t) {
    const int tn = (t + 1 < ITERS) ? t + 1 : t;  // clamped (uniform count)
    // ---- issue tile t+1 loads (10 VMEM) ----
    float4 a0n = *reinterpret_cast<const float4*>(xp + 32 * tn);
    float4 a1n = *reinterpret_cast<const float4*>(xp + 32 * tn + 4);
    bf16x8 BHn[4], BLn[4];
#pragma unroll
    for (int j = 0; j < 4; ++j) {
      BHn[j] = *reinterpret_cast<const bf16x8*>(bh + (size_t)tn * 2048 + j * 512);
      BLn[j] = *reinterpret_cast<const bf16x8*>(bl + (size_t)tn * 2048 + j * 512);
    }
    __builtin_amdgcn_sched_barrier(0);  // loads stay ABOVE the compute
    // ---- compute tile t (term-major; per-acc order: LL, LH, HL, HH) ----
    bf16x8 Ahi, Alo;
    split8(a0c, a1c, Ahi, Alo);
#pragma unroll
    for (int j = 0; j < 4; ++j)
      acc[j] = __builtin_amdgcn_mfma_f32_16x16x32_bf16(Alo, BLc[j], acc[j], 0, 0, 0);
#pragma unroll
    for (int j = 0; j < 4; ++j)
      acc[j] = __builtin_amdgcn_mfma_f32_16x16x32_bf16(Alo, BHc[j], acc[j], 0, 0, 0);
#pragma unroll
    for (int j = 0; j < 4; ++j)
      acc[j] = __builtin_amdgcn_mfma_f32_16x16x32_bf16(Ahi, BLc[j], acc[j], 0, 0, 0);
#pragma unroll
    for (int j = 0; j < 4; ++j)
      acc[j] = __builtin_amdgcn_mfma_f32_16x16x32_bf16(Ahi, BHc[j], acc[j], 0, 0, 0);
    __builtin_amdgcn_sched_barrier(0);  // rotate stays below
    a0c = a0n;
    a1c = a1n;
#pragma unroll
    for (int j = 0; j < 4; ++j) {
      BHc[j] = BHn[j];
      BLc[j] = BLn[j];
    }
  }

  // ---- epilogue: K-split reduction, then fused softmax/top-9 -------------
  // C frag (HW-validated r5): token-within-16 = 4*lk + r, expert = 16*j + lr.
  if (kh == 1) {
#pragma unroll
    for (int j = 0; j < 4; ++j)
#pragma unroll
      for (int r = 0; r < 4; ++r)
        Ls[(16 * tg + 4 * lk + r) * LSTR + 16 * j + lr] = acc[j][r];
  }
  __syncthreads();
  if (kh == 0) {
#pragma unroll
    for (int j = 0; j < 4; ++j)
#pragma unroll
      for (int r = 0; r < 4; ++r)
        acc[j][r] += Ls[(16 * tg + 4 * lk + r) * LSTR + 16 * j + lr];
  }
  __syncthreads();
  if (kh == 0) {
#pragma unroll
    for (int j = 0; j < 4; ++j)
#pragma unroll
      for (int r = 0; r < 4; ++r)
        Ls[(16 * tg + 4 * lk + r) * LSTR + 16 * j + lr] = acc[j][r];
  }
  __syncthreads();

  if (kh == 0) {
    const float bv = bias[lane];
    for (int tt = 0; tt < 16; ++tt) {
      const int tl = tg * 16 + tt;
      const int t = row0 + tl;
      const float s = Ls[tl * LSTR + lane] + bv;

      float m = s;
#pragma unroll
      for (int off = 32; off >= 1; off >>= 1) m = fmaxf(m, __shfl_xor(m, off));
      const float e = expf(s - m);
      float sum = e;
#pragma unroll
      for (int off = 32; off >= 1; off >>= 1) sum += __shfl_xor(sum, off);
      const float p = e / sum;

      // top-9 on biased raw score, lowest-index tie-break (lax.top_k)
      float wsel = s;
      float rv = 0.f;
      int ri = 0;
      float prev = 0.f, mingap = 1e30f;
#pragma unroll
      for (int r = 0; r < 9; ++r) {
        float v = wsel;
        int ii = lane;
#pragma unroll
        for (int off = 32; off >= 1; off >>= 1) {
          const float ov = __shfl_xor(v, off);
          const int oi = __shfl_xor(ii, off);
          if (ov > v || (ov == v && oi < ii)) { v = ov; ii = oi; }
        }
        if (r > 0) mingap = fminf(mingap, prev - v);
        prev = v;
        const float pw = __shfl(p, ii);
        if (lane == r) { rv = pw; ri = ii; }
        if (lane == ii) wsel = -1e30f;
      }

      bool toC = false;
      if (mingap < TAU && cap > 0) {
        int pos = 0;
        if (lane == 0) pos = atomicAdd(cnt, 1);
        pos = __shfl(pos, 0);
        if (pos < cap) {
          if (lane == 0) list[pos] = t;
          toC = true;  // recompute kernel produces all outputs for this token
        }
      }
      if (!toC) {
        S[(size_t)t * NE + lane] = p;
        if (lane < K) {
          wout[(size_t)t * K + lane] = rv;
          iout[(size_t)t * K + lane] = (float)ri;
          atomicAdd(&hist_s[ri], 1);
        }
      }
    }
  }
  __syncthreads();
  if (tid < NE) atomicAdd(&hist[tid], hist_s[tid]);
}

// -------- f64 finalize for one token (lanes 0..63) ---------------
__device__ __forceinline__ void finalize_token_f64(
    int t, int lane, double s, float* __restrict__ S, float* __restrict__ wout,
    float* __restrict__ iout, int* __restrict__ hist, int K) {
  double m = s;
#pragma unroll
  for (int off = 32; off >= 1; off >>= 1) m = fmax(m, __shfl_xor(m, off));
  const double ex = exp(s - m);
  double sum = ex;
#pragma unroll
  for (int off = 32; off >= 1; off >>= 1) sum += __shfl_xor(sum, off);
  const double p = ex / sum;
  S[(size_t)t * NE + lane] = (float)p;
  double wsel = s;
  double rv = 0.0;
  int ri = 0;
  for (int r = 0; r < K; ++r) {
    double v = wsel;
    int ii = lane;
#pragma unroll
    for (int off = 32; off >= 1; off >>= 1) {
      const double ov = __shfl_xor(v, off);
      const int oi = __shfl_xor(ii, off);
      if (ov > v || (ov == v && oi < ii)) { v = ov; ii = oi; }
    }
    const double pw = __shfl(p, ii);
    if (lane == r) { rv = pw; ri = ii; }
    if (lane == ii) wsel = -1e300;
  }
  if (lane < K) {
    wout[(size_t)t * K + lane] = (float)rv;
    iout[(size_t)t * K + lane] = (float)ri;
    atomicAdd(&hist[ri], 1);
  }
}

// ------- Kernel 2: f64 recompute, 1 token/block, grid 512 -------------------
__global__ __launch_bounds__(256) void recompute_f64(
    const float* __restrict__ X, const float* __restrict__ W,
    const float* __restrict__ bias, float* __restrict__ S,
    float* __restrict__ wout, float* __restrict__ iout,
    const int* __restrict__ cnt, const int* __restrict__ list,
    int* __restrict__ hist, int H, int K, int cap) {
  if (cap <= 0) return;
  __shared__ float4 xs[1024];  // one token row (16 KB)
  __shared__ double red[256];
  const int tid = threadIdx.x;
  const int n = min(*cnt, cap);
  const int H4 = H >> 2;
  for (int idx = blockIdx.x; idx < n; idx += gridDim.x) {
    const int t = list[idx];
    __syncthreads();  // xs reuse from previous iteration
    const float4* xg = reinterpret_cast<const float4*>(X + (size_t)t * H);
    for (int i = tid; i < H4; i += 256) xs[i] = xg[i];
    __syncthreads();
    const int e = tid & 63, sl = tid >> 6;
    const int seg = H4 >> 2;  // 256 float4 per slice
    const float4* wr =
        reinterpret_cast<const float4*>(W + (size_t)e * H) + (size_t)sl * seg;
    const float4* xr = &xs[sl * seg];
    double a0 = 0.0, a1 = 0.0;  // split accumulators (break f64 dep chain)
    for (int k = 0; k < seg; k += 2) {
      const float4 w0 = wr[k], w1 = wr[k + 1];
      const float4 v0 = xr[k], v1 = xr[k + 1];
      a0 = fma((double)v0.x, (double)w0.x, a0);
      a0 = fma((double)v0.y, (double)w0.y, a0);
      a0 = fma((double)v0.z, (double)w0.z, a0);
      a0 = fma((double)v0.w, (double)w0.w, a0);
      a1 = fma((double)v1.x, (double)w1.x, a1);
      a1 = fma((double)v1.y, (double)w1.y, a1);
      a1 = fma((double)v1.z, (double)w1.z, a1);
      a1 = fma((double)v1.w, (double)w1.w, a1);
    }
    red[tid] = a0 + a1;
    __syncthreads();
    if (tid < 64) {
      const double s =
          red[e] + red[64 + e] + red[128 + e] + red[192 + e] + (double)bias[e];
      finalize_token_f64(t, e, s, S, wout, iout, hist, K);
    }
  }
}

// ------------- Kernel 3: bias update from integer histogram -----------------
__global__ void bias_update(const int* __restrict__ hist,
                            const float* __restrict__ bias,
                            float* __restrict__ bout, float tpe) {
  const int e = threadIdx.x;
  const float d = (float)hist[e] - tpe;
  const float sg = (d > 0.f) ? 1.f : ((d < 0.f) ? -1.f : 0.f);
  bout[e] = bias[e] + 0.01f * sg;
}

extern "C" void kernel_launch(void* const* d_in, const int* in_sizes, int n_in,
                              void* d_out, int out_size, void* d_ws, size_t ws_size,
                              hipStream_t stream) {
  const float* x = (const float*)d_in[0];
  const float* w = (const float*)d_in[1];
  const float* bias = (const float*)d_in[2];
  const int E = in_sizes[2];                       // 64
  const int H = in_sizes[1] / E;                   // 4096
  const long long N = (long long)in_sizes[0] / H;  // 32768 tokens
  const int K = (int)(((long long)out_size - N * E - E) / (2 * N));  // 8

  float* S = (float*)d_out;            // [N][E] probs
  float* wout = S + (size_t)N * E;     // [N][K]
  float* iout = wout + (size_t)N * K;  // [N][K] indices as float
  float* bout = iout + (size_t)N * K;  // [E]

  // ws: [0,4) cnt | [256,512) hist | Whi_f @4KB (512KB) | Wlo_f | list after
  int* cnt = (int*)d_ws;
  int* hist = (int*)d_ws + 64;
  const size_t whalf = (size_t)E * H * sizeof(__bf16);  // 512 KB
  __bf16* Whi = (__bf16*)((char*)d_ws + 4096);
  __bf16* Wlo = (__bf16*)((char*)d_ws + 4096 + whalf);
  const size_t listoff = 4096 + 2 * whalf;
  int* list = (int*)((char*)d_ws + listoff);
  int cap = 0;
  if (ws_size > listoff + 65536)
    cap = (int)min((size_t)32768, (ws_size - listoff) / 4);

  zero512<<<dim3(1), dim3(128), 0, stream>>>((int*)d_ws);
  const int n8 = E * H / 8;
  wconvert<<<dim3((n8 + 255) / 256), 256, 0, stream>>>(w, Whi, Wlo, n8, H);
  gemm_fused<<<dim3((int)(N / 32)), 256, 0, stream>>>(
      x, Whi, Wlo, bias, S, wout, iout, cnt, hist, list, cap, H, K);
  recompute_f64<<<dim3(512), 256, 0, stream>>>(x, w, bias, S, wout, iout, cnt,
                                               list, hist, H, K, cap);
  bias_update<<<dim3(1), dim3(E), 0, stream>>>(hist, bias, bout,
                                               (float)((double)N * K / E));
}

// Round 13
// 300.736 us; speedup vs baseline: 1.1195x; 1.1195x over previous
//
#include <hip/hip_runtime.h>

#define NE 64
#define TAU 1e-4f  // 4-term split-bf16 score sigma ~5e-6 -> 20-sigma guard
#define LSTR 68    // 68 mod 32 = 4 -> 2-way (free) LDS access in epilogue

typedef __bf16 bf16x8 __attribute__((ext_vector_type(8)));
typedef float f32x4 __attribute__((ext_vector_type(4)));

// split f32 -> bf16 hi + bf16 lo (hi RNE, lo = RNE(x - hi); x-hi exact in f32)
__device__ __forceinline__ void split8(const float4 a0, const float4 a1,
                                       bf16x8& hi, bf16x8& lo) {
  const float xs[8] = {a0.x, a0.y, a0.z, a0.w, a1.x, a1.y, a1.z, a1.w};
#pragma unroll
  for (int i = 0; i < 8; ++i) {
    const __bf16 h = (__bf16)xs[i];
    hi[i] = h;
    lo[i] = (__bf16)(xs[i] - (float)h);
  }
}

// async global->LDS, 16B/lane; LDS dest = wave-uniform base + lane*16
__device__ __forceinline__ void gld16(const void* g, void* l) {
  __builtin_amdgcn_global_load_lds(
      (const __attribute__((address_space(1))) void*)g,
      (__attribute__((address_space(3))) void*)l, 16, 0, 0);
}

// ---- Kernel Z: zero cnt+hist ------------------------------------------------
__global__ void zero512(int* __restrict__ p) { p[threadIdx.x] = 0; }

// ---- Kernel 0: W -> bf16 hi/lo in FRAGMENT-MAJOR 32-k tiles (1 MB, once) ---
// elem(tt, j, lk, lr, kr) = tt*2048 + j*512 + (lk*16+lr)*8 + kr
// where W-row e = 16j+lr, k = 32tt + 8lk + kr. K-slice s = tts [16s,16s+16)
// is 32768 contiguous elements (64 KB) -> trivially DMA-able to LDS.
__global__ __launch_bounds__(256) void wconvert(const float* __restrict__ W,
                                                __bf16* __restrict__ Whi,
                                                __bf16* __restrict__ Wlo,
                                                int n8, int H) {
  const int i = blockIdx.x * 256 + threadIdx.x;
  if (i >= n8) return;
  const int hc = H >> 3;
  const int e = i / hc;
  const int k0 = (i - e * hc) * 8;
  const float4 a0 = *reinterpret_cast<const float4*>(W + (size_t)e * H + k0);
  const float4 a1 =
      *reinterpret_cast<const float4*>(W + (size_t)e * H + k0 + 4);
  bf16x8 hi, lo;
  split8(a0, a1, hi, lo);
  const int tt = k0 >> 5, lk = (k0 >> 3) & 3, j = e >> 4, lr = e & 15;
  const size_t off = (size_t)tt * 2048 + j * 512 + (lk * 16 + lr) * 8;
  *reinterpret_cast<bf16x8*>(Whi + off) = hi;
  *reinterpret_cast<bf16x8*>(Wlo + off) = lo;
}

// ------- Kernel 1: block-stationary-B split-bf16 MFMA GEMM ------------------
// grid = N/128 = 256 blocks (1/CU). 8 waves x 16 tokens = 128 tokens/block.
// acc persists across 8 K-slices (no partials). Per slice: DMA B-slice
// (128 KB: hi+lo fragment-major) into LDS once, then 16 BARRIER-FREE k-steps:
// 2 per-lane A loads (1-ahead register rotation) + 8 conflict-free
// lane-contiguous ds_read_b128 + 16 MFMA (4-term split-bf16).
__global__ __launch_bounds__(512, 2) void gemm_fused(
    const float* __restrict__ X, const __bf16* __restrict__ Whi,
    const __bf16* __restrict__ Wlo, const float* __restrict__ bias,
    float* __restrict__ S, float* __restrict__ wout, float* __restrict__ iout,
    int* __restrict__ cnt, int* __restrict__ hist, int* __restrict__ list,
    int cap, int H, int K) {
  __shared__ alignas(16) char smem[131072];  // B-slice hi (64K) + lo (64K)
  __shared__ int hist_s[NE];
  const int tid = threadIdx.x;
  const int lane = tid & 63;
  const int wave = tid >> 6;  // 0..7
  if (tid < NE) hist_s[tid] = 0;
  const int lr = lane & 15;
  const int lk = lane >> 4;
  const int row0 = blockIdx.x * 128;

  __bf16* BH = (__bf16*)smem;             // [16 steps][4 j][64 lane][8]
  __bf16* BL = (__bf16*)(smem + 65536);

  const float* xp = X + (size_t)(row0 + 16 * wave + lr) * H + 8 * lk;
  const int T = (H >> 5);            // 128 total 32-k steps
  const int NSL = T >> 4;            // 8 slices

  f32x4 acc[4] = {};
  // A prologue: step 0
  float4 aC0 = *reinterpret_cast<const float4*>(xp);
  float4 aC1 = *reinterpret_cast<const float4*>(xp + 4);

  for (int s = 0; s < NSL; ++s) {
    if (s) __syncthreads();  // all waves done reading previous slice
    // ---- DMA B-slice s (each wave stages 8 KB of hi + 8 KB of lo) ----
    const __bf16* sh = Whi + (size_t)s * 32768 + wave * 4096 + lane * 8;
    const __bf16* sl = Wlo + (size_t)s * 32768 + wave * 4096 + lane * 8;
#pragma unroll
    for (int i = 0; i < 8; ++i) {
      gld16(sh + i * 512, BH + wave * 4096 + i * 512);
      gld16(sl + i * 512, BL + wave * 4096 + i * 512);
    }
    asm volatile("s_waitcnt vmcnt(0)" ::: "memory");
    __syncthreads();  // slice resident for all waves

    // ---- 16 barrier-free k-steps ----
#pragma unroll 4
    for (int st = 0; st < 16; ++st) {
      const int t = s * 16 + st;
      const int tn = (t + 1 < T) ? t + 1 : t;
      const float4 aN0 = *reinterpret_cast<const float4*>(xp + 32 * tn);
      const float4 aN1 = *reinterpret_cast<const float4*>(xp + 32 * tn + 4);
      bf16x8 Ahi, Alo;
      split8(aC0, aC1, Ahi, Alo);
      const __bf16* bh = BH + st * 2048 + lane * 8;
      const __bf16* bl = BL + st * 2048 + lane * 8;
      bf16x8 BHf[4], BLf[4];
#pragma unroll
      for (int j = 0; j < 4; ++j) {
        BHf[j] = *reinterpret_cast<const bf16x8*>(bh + j * 512);
        BLf[j] = *reinterpret_cast<const bf16x8*>(bl + j * 512);
      }
      // term-major; per-acc order LL, LH, HL, HH (same as rounds 10-12)
#pragma unroll
      for (int j = 0; j < 4; ++j)
        acc[j] = __builtin_amdgcn_mfma_f32_16x16x32_bf16(Alo, BLf[j], acc[j], 0, 0, 0);
#pragma unroll
      for (int j = 0; j < 4; ++j)
        acc[j] = __builtin_amdgcn_mfma_f32_16x16x32_bf16(Alo, BHf[j], acc[j], 0, 0, 0);
#pragma unroll
      for (int j = 0; j < 4; ++j)
        acc[j] = __builtin_amdgcn_mfma_f32_16x16x32_bf16(Ahi, BLf[j], acc[j], 0, 0, 0);
#pragma unroll
      for (int j = 0; j < 4; ++j)
        acc[j] = __builtin_amdgcn_mfma_f32_16x16x32_bf16(Ahi, BHf[j], acc[j], 0, 0, 0);
      aC0 = aN0;
      aC1 = aN1;
    }
  }

  // ---- epilogue: transpose scores to token-major LDS (aliases smem) ----
  __syncthreads();
  float* Ls = (float*)smem;  // 128*68*4 = 34816 B <= 131072
#pragma unroll
  for (int j = 0; j < 4; ++j)
#pragma unroll
    for (int r = 0; r < 4; ++r)
      Ls[(16 * wave + 4 * lk + r) * LSTR + 16 * j + lr] = acc[j][r];
  __syncthreads();

  const float bv = bias[lane];
  for (int tt = 0; tt < 16; ++tt) {
    const int tl = wave * 16 + tt;
    const int t = row0 + tl;
    const float s = Ls[tl * LSTR + lane] + bv;

    float m = s;
#pragma unroll
    for (int off = 32; off >= 1; off >>= 1) m = fmaxf(m, __shfl_xor(m, off));
    const float e = expf(s - m);
    float sum = e;
#pragma unroll
    for (int off = 32; off >= 1; off >>= 1) sum += __shfl_xor(sum, off);
    const float p = e / sum;

    // top-9 on biased raw score, lowest-index tie-break (matches lax.top_k)
    float wsel = s;
    float rv = 0.f;
    int ri = 0;
    float prev = 0.f, mingap = 1e30f;
#pragma unroll
    for (int r = 0; r < 9; ++r) {
      float v = wsel;
      int ii = lane;
#pragma unroll
      for (int off = 32; off >= 1; off >>= 1) {
        const float ov = __shfl_xor(v, off);
        const int oi = __shfl_xor(ii, off);
        if (ov > v || (ov == v && oi < ii)) { v = ov; ii = oi; }
      }
      if (r > 0) mingap = fminf(mingap, prev - v);
      prev = v;
      const float pw = __shfl(p, ii);
      if (lane == r) { rv = pw; ri = ii; }
      if (lane == ii) wsel = -1e30f;
    }

    bool toC = false;
    if (mingap < TAU && cap > 0) {
      int pos = 0;
      if (lane == 0) pos = atomicAdd(cnt, 1);
      pos = __shfl(pos, 0);
      if (pos < cap) {
        if (lane == 0) list[pos] = t;
        toC = true;  // recompute kernel produces all outputs for this token
      }
    }
    if (!toC) {
      S[(size_t)t * NE + lane] = p;
      if (lane < K) {
        wout[(size_t)t * K + lane] = rv;
        iout[(size_t)t * K + lane] = (float)ri;
        atomicAdd(&hist_s[ri], 1);
      }
    }
  }
  __syncthreads();
  if (tid < NE) atomicAdd(&hist[tid], hist_s[tid]);
}

// -------- f64 finalize for one token (lanes 0..63) ---------------
__device__ __forceinline__ void finalize_token_f64(
    int t, int lane, double s, float* __restrict__ S, float* __restrict__ wout,
    float* __restrict__ iout, int* __restrict__ hist, int K) {
  double m = s;
#pragma unroll
  for (int off = 32; off >= 1; off >>= 1) m = fmax(m, __shfl_xor(m, off));
  const double ex = exp(s - m);
  double sum = ex;
#pragma unroll
  for (int off = 32; off >= 1; off >>= 1) sum += __shfl_xor(sum, off);
  const double p = ex / sum;
  S[(size_t)t * NE + lane] = (float)p;
  double wsel = s;
  double rv = 0.0;
  int ri = 0;
  for (int r = 0; r < K; ++r) {
    double v = wsel;
    int ii = lane;
#pragma unroll
    for (int off = 32; off >= 1; off >>= 1) {
      const double ov = __shfl_xor(v, off);
      const int oi = __shfl_xor(ii, off);
      if (ov > v || (ov == v && oi < ii)) { v = ov; ii = oi; }
    }
    const double pw = __shfl(p, ii);
    if (lane == r) { rv = pw; ri = ii; }
    if (lane == ii) wsel = -1e300;
  }
  if (lane < K) {
    wout[(size_t)t * K + lane] = (float)rv;
    iout[(size_t)t * K + lane] = (float)ri;
    atomicAdd(&hist[ri], 1);
  }
}

// ------- Kernel 2: f64 recompute, 1 token/block, grid 512 -------------------
__global__ __launch_bounds__(256) void recompute_f64(
    const float* __restrict__ X, const float* __restrict__ W,
    const float* __restrict__ bias, float* __restrict__ S,
    float* __restrict__ wout, float* __restrict__ iout,
    const int* __restrict__ cnt, const int* __restrict__ list,
    int* __restrict__ hist, int H, int K, int cap) {
  if (cap <= 0) return;
  __shared__ float4 xs[1024];  // one token row (16 KB)
  __shared__ double red[256];
  const int tid = threadIdx.x;
  const int n = min(*cnt, cap);
  const int H4 = H >> 2;
  for (int idx = blockIdx.x; idx < n; idx += gridDim.x) {
    const int t = list[idx];
    __syncthreads();  // xs reuse from previous iteration
    const float4* xg = reinterpret_cast<const float4*>(X + (size_t)t * H);
    for (int i = tid; i < H4; i += 256) xs[i] = xg[i];
    __syncthreads();
    const int e = tid & 63, sl = tid >> 6;
    const int seg = H4 >> 2;  // 256 float4 per slice
    const float4* wr =
        reinterpret_cast<const float4*>(W + (size_t)e * H) + (size_t)sl * seg;
    const float4* xr = &xs[sl * seg];
    double a0 = 0.0, a1 = 0.0;  // split accumulators (break f64 dep chain)
    for (int k = 0; k < seg; k += 2) {
      const float4 w0 = wr[k], w1 = wr[k + 1];
      const float4 v0 = xr[k], v1 = xr[k + 1];
      a0 = fma((double)v0.x, (double)w0.x, a0);
      a0 = fma((double)v0.y, (double)w0.y, a0);
      a0 = fma((double)v0.z, (double)w0.z, a0);
      a0 = fma((double)v0.w, (double)w0.w, a0);
      a1 = fma((double)v1.x, (double)w1.x, a1);
      a1 = fma((double)v1.y, (double)w1.y, a1);
      a1 = fma((double)v1.z, (double)w1.z, a1);
      a1 = fma((double)v1.w, (double)w1.w, a1);
    }
    red[tid] = a0 + a1;
    __syncthreads();
    if (tid < 64) {
      const double s =
          red[e] + red[64 + e] + red[128 + e] + red[192 + e] + (double)bias[e];
      finalize_token_f64(t, e, s, S, wout, iout, hist, K);
    }
  }
}

// ------------- Kernel 3: bias update from integer histogram -----------------
__global__ void bias_update(const int* __restrict__ hist,
                            const float* __restrict__ bias,
                            float* __restrict__ bout, float tpe) {
  const int e = threadIdx.x;
  const float d = (float)hist[e] - tpe;
  const float sg = (d > 0.f) ? 1.f : ((d < 0.f) ? -1.f : 0.f);
  bout[e] = bias[e] + 0.01f * sg;
}

extern "C" void kernel_launch(void* const* d_in, const int* in_sizes, int n_in,
                              void* d_out, int out_size, void* d_ws, size_t ws_size,
                              hipStream_t stream) {
  const float* x = (const float*)d_in[0];
  const float* w = (const float*)d_in[1];
  const float* bias = (const float*)d_in[2];
  const int E = in_sizes[2];                       // 64
  const int H = in_sizes[1] / E;                   // 4096
  const long long N = (long long)in_sizes[0] / H;  // 32768 tokens
  const int K = (int)(((long long)out_size - N * E - E) / (2 * N));  // 8

  float* S = (float*)d_out;            // [N][E] probs
  float* wout = S + (size_t)N * E;     // [N][K]
  float* iout = wout + (size_t)N * K;  // [N][K] indices as float
  float* bout = iout + (size_t)N * K;  // [E]

  // ws: [0,4) cnt | [256,512) hist | Whi_f @4KB (512KB) | Wlo_f | list after
  int* cnt = (int*)d_ws;
  int* hist = (int*)d_ws + 64;
  const size_t whalf = (size_t)E * H * sizeof(__bf16);  // 512 KB
  __bf16* Whi = (__bf16*)((char*)d_ws + 4096);
  __bf16* Wlo = (__bf16*)((char*)d_ws + 4096 + whalf);
  const size_t listoff = 4096 + 2 * whalf;
  int* list = (int*)((char*)d_ws + listoff);
  int cap = 0;
  if (ws_size > listoff + 65536)
    cap = (int)min((size_t)32768, (ws_size - listoff) / 4);

  zero512<<<dim3(1), dim3(128), 0, stream>>>((int*)d_ws);
  const int n8 = E * H / 8;
  wconvert<<<dim3((n8 + 255) / 256), 256, 0, stream>>>(w, Whi, Wlo, n8, H);
  gemm_fused<<<dim3((int)(N / 128)), 512, 0, stream>>>(
      x, Whi, Wlo, bias, S, wout, iout, cnt, hist, list, cap, H, K);
  recompute_f64<<<dim3(512), 256, 0, stream>>>(x, w, bias, S, wout, iout, cnt,
                                               list, hist, H, K, cap);
  bias_update<<<dim3(1), dim3(E), 0, stream>>>(hist, bias, bout,
                                               (float)((double)N * K / E));
}

// Round 15
// 299.607 us; speedup vs baseline: 1.1237x; 1.0038x over previous
//
#include <hip/hip_runtime.h>

#define NE 64
#define TAU 1e-4f  // 4-term split-bf16 score sigma ~5e-6 -> 20-sigma guard
#define LSTR 68    // 68 mod 32 = 4 -> 2-way (free) LDS access in epilogue

typedef __bf16 bf16x8 __attribute__((ext_vector_type(8)));
typedef float f32x4 __attribute__((ext_vector_type(4)));

// split f32 -> bf16 hi + bf16 lo (hi RNE, lo = RNE(x - hi); x-hi exact in f32)
__device__ __forceinline__ void split8(const float4 a0, const float4 a1,
                                       bf16x8& hi, bf16x8& lo) {
  const float xs[8] = {a0.x, a0.y, a0.z, a0.w, a1.x, a1.y, a1.z, a1.w};
#pragma unroll
  for (int i = 0; i < 8; ++i) {
    const __bf16 h = (__bf16)xs[i];
    hi[i] = h;
    lo[i] = (__bf16)(xs[i] - (float)h);
  }
}

// async global->LDS, 16B/lane; LDS dest = wave-uniform base + lane*16
__device__ __forceinline__ void gld16(const void* g, void* l) {
  __builtin_amdgcn_global_load_lds(
      (const __attribute__((address_space(1))) void*)g,
      (__attribute__((address_space(3))) void*)l, 16, 0, 0);
}

// ---- Kernel Z: zero cnt+hist ------------------------------------------------
__global__ void zero512(int* __restrict__ p) { p[threadIdx.x] = 0; }

// ---- Kernel 0: W -> bf16 hi/lo in FRAGMENT-MAJOR 32-k tiles (1 MB, once) ---
// elem(tt, j, lk, lr, kr) = tt*2048 + j*512 + (lk*16+lr)*8 + kr
// where W-row e = 16j+lr, k = 32tt + 8lk + kr.
__global__ __launch_bounds__(256) void wconvert(const float* __restrict__ W,
                                                __bf16* __restrict__ Whi,
                                                __bf16* __restrict__ Wlo,
                                                int n8, int H) {
  const int i = blockIdx.x * 256 + threadIdx.x;
  if (i >= n8) return;
  const int hc = H >> 3;
  const int e = i / hc;
  const int k0 = (i - e * hc) * 8;
  const float4 a0 = *reinterpret_cast<const float4*>(W + (size_t)e * H + k0);
  const float4 a1 =
      *reinterpret_cast<const float4*>(W + (size_t)e * H + k0 + 4);
  bf16x8 hi, lo;
  split8(a0, a1, hi, lo);
  const int tt = k0 >> 5, lk = (k0 >> 3) & 3, j = e >> 4, lr = e & 15;
  const size_t off = (size_t)tt * 2048 + j * 512 + (lk * 16 + lr) * 8;
  *reinterpret_cast<bf16x8*>(Whi + off) = hi;
  *reinterpret_cast<bf16x8*>(Wlo + off) = lo;
}

// ---- staging/compute helpers, COMPILE-TIME buffer index, BK=32 -------------
// LDS map (bytes): A[buf] at buf*8192 (8 KB), Bh[buf] at 16384+buf*4096,
// Bl[buf] at 24576+buf*4096. Total 32 KB -> 4 blocks/CU.
// A-wave layout: [p(2)][row rr&7][phys chunk 0..7 of 16B], chunk swizzle
// phys = logical ^ (rr&7), applied on the pre-swizzled GLOBAL source.
template <int BUF>
__device__ __forceinline__ void issue_tile(int t, const float* srcA0,
                                           const float* srcA1,
                                           const __bf16* srcBh,
                                           const __bf16* srcBl, char* smem,
                                           int wave) {
  float* af = (float*)smem + BUF * 2048;
  __bf16* bh = (__bf16*)(smem + 16384) + BUF * 2048;
  __bf16* bl = (__bf16*)(smem + 24576) + BUF * 2048;
  gld16(srcA0 + 32 * (size_t)t, af + wave * 512);
  gld16(srcA1 + 32 * (size_t)t, af + wave * 512 + 256);
  gld16(srcBh + 2048 * (size_t)t, bh + wave * 512);
  gld16(srcBl + 2048 * (size_t)t, bl + wave * 512);
}

template <int BUF>
__device__ __forceinline__ void compute_tile(char* smem, int wave, int lane,
                                             int lr, int lk, f32x4 (&acc)[4]) {
  const float* Aw = (float*)smem + BUF * 2048 + wave * 512 + (lr >> 3) * 256 +
                    (lr & 7) * 32;
  const int s0 = (2 * lk) ^ (lr & 7);
  const int s1 = (2 * lk + 1) ^ (lr & 7);
  const float4 f0 = *reinterpret_cast<const float4*>(Aw + s0 * 4);
  const float4 f1 = *reinterpret_cast<const float4*>(Aw + s1 * 4);
  const __bf16* Bh0 = (__bf16*)(smem + 16384) + BUF * 2048;
  const __bf16* Bl0 = (__bf16*)(smem + 24576) + BUF * 2048;
  bf16x8 BHf[4], BLf[4];
#pragma unroll
  for (int j = 0; j < 4; ++j) {
    BHf[j] = *reinterpret_cast<const bf16x8*>(Bh0 + j * 512 + lane * 8);
    BLf[j] = *reinterpret_cast<const bf16x8*>(Bl0 + j * 512 + lane * 8);
  }
  bf16x8 Ahi, Alo;
  split8(f0, f1, Ahi, Alo);
#pragma unroll
  for (int j = 0; j < 4; ++j)
    acc[j] = __builtin_amdgcn_mfma_f32_16x16x32_bf16(Alo, BLf[j], acc[j], 0, 0, 0);
#pragma unroll
  for (int j = 0; j < 4; ++j)
    acc[j] = __builtin_amdgcn_mfma_f32_16x16x32_bf16(Alo, BHf[j], acc[j], 0, 0, 0);
#pragma unroll
  for (int j = 0; j < 4; ++j)
    acc[j] = __builtin_amdgcn_mfma_f32_16x16x32_bf16(Ahi, BLf[j], acc[j], 0, 0, 0);
#pragma unroll
  for (int j = 0; j < 4; ++j)
    acc[j] = __builtin_amdgcn_mfma_f32_16x16x32_bf16(Ahi, BHf[j], acc[j], 0, 0, 0);
}

// ------- Kernel 1: 4-term split-bf16 MFMA GEMM, BK=32, K-split 2 ------------
// grid (N/64, 2). blockIdx.y picks K-half; partial scores -> P (S or P2).
// 32 KB LDS + launch_bounds(256,4) -> 4 resident blocks/CU (m132/m114:
// staggered blocks hide the per-iter barrier drains).
__global__ __launch_bounds__(256, 4) void gemm_half(
    const float* __restrict__ X, const __bf16* __restrict__ Whi,
    const __bf16* __restrict__ Wlo, float* __restrict__ S0,
    float* __restrict__ P2, int H) {
  __shared__ alignas(16) char smem[32768];
  const int tid = threadIdx.x;
  const int lane = tid & 63;
  const int wave = tid >> 6;
  const int lr = lane & 15;
  const int lk = lane >> 4;
  const int row0 = blockIdx.x * 64;
  const int kbeg = blockIdx.y * (H >> 1);
  float* __restrict__ P = blockIdx.y ? P2 : S0;

  // A staging sources (pre-swizzled): instr p, lane -> row rr = 8p+(lane>>3),
  // phys chunk sp = lane&7 holds logical chunk sp ^ (rr&7).
  const int rr0 = lane >> 3;
  const int sp = lane & 7;
  const float* srcA0 =
      X + (size_t)(row0 + 16 * wave + rr0) * H + kbeg + 4 * (sp ^ rr0);
  const float* srcA1 =
      X + (size_t)(row0 + 16 * wave + 8 + rr0) * H + kbeg + 4 * (sp ^ rr0);
  const __bf16* srcBh =
      Whi + (size_t)(blockIdx.y * 64) * 2048 + wave * 512 + lane * 8;
  const __bf16* srcBl =
      Wlo + (size_t)(blockIdx.y * 64) * 2048 + wave * 512 + lane * 8;

  f32x4 acc[4] = {};
  const int T2 = H >> 6;  // 64 tiles per K-half

  issue_tile<0>(0, srcA0, srcA1, srcBh, srcBl, smem, wave);
  for (int t = 0; t < T2; t += 2) {
    if (t + 1 < T2) {
      issue_tile<1>(t + 1, srcA0, srcA1, srcBh, srcBl, smem, wave);
      asm volatile("s_waitcnt vmcnt(4)" ::: "memory");  // tile t landed
    } else {
      asm volatile("s_waitcnt vmcnt(0)" ::: "memory");
    }
    __builtin_amdgcn_s_barrier();
    asm volatile("" ::: "memory");
    compute_tile<0>(smem, wave, lane, lr, lk, acc);
    asm volatile("" ::: "memory");
    __builtin_amdgcn_s_barrier();
    asm volatile("" ::: "memory");
    if (t + 2 < T2) {
      issue_tile<0>(t + 2, srcA0, srcA1, srcBh, srcBl, smem, wave);
      asm volatile("s_waitcnt vmcnt(4)" ::: "memory");  // tile t+1 landed
    } else {
      asm volatile("s_waitcnt vmcnt(0)" ::: "memory");
    }
    __builtin_amdgcn_s_barrier();
    asm volatile("" ::: "memory");
    compute_tile<1>(smem, wave, lane, lr, lk, acc);
    asm volatile("" ::: "memory");
    __builtin_amdgcn_s_barrier();
    asm volatile("" ::: "memory");
  }

  // ---- epilogue: transpose to token-major, write partial rows coalesced ----
  __syncthreads();
  float* Ls = (float*)smem;  // 64*68*4 = 17408 <= 32768
#pragma unroll
  for (int j = 0; j < 4; ++j)
#pragma unroll
    for (int r = 0; r < 4; ++r)
      Ls[(16 * wave + 4 * lk + r) * LSTR + 16 * j + lr] = acc[j][r];
  __syncthreads();
  for (int tt = 0; tt < 16; ++tt) {
    const int tl = wave * 16 + tt;
    P[(size_t)(row0 + tl) * NE + lane] = Ls[tl * LSTR + lane];
  }
}

// ------- Kernel 2: merge halves + softmax + top-9 + deferral + hist ---------
__global__ __launch_bounds__(256) void finish(
    const float* __restrict__ P2, const float* __restrict__ bias,
    float* __restrict__ S, float* __restrict__ wout, float* __restrict__ iout,
    int* __restrict__ cnt, int* __restrict__ hist, int* __restrict__ list,
    int cap, int K) {
  __shared__ int hist_s[NE];
  const int tid = threadIdx.x;
  if (tid < NE) hist_s[tid] = 0;
  __syncthreads();
  const int lane = tid & 63;
  const int wave = tid >> 6;
  const float bv = bias[lane];
  const int t0 = blockIdx.x * 64 + wave * 16;

  for (int tt = 0; tt < 16; ++tt) {
    const int t = t0 + tt;
    const size_t base = (size_t)t * NE;
    const float s = S[base + lane] + P2[base + lane] + bv;

    float m = s;
#pragma unroll
    for (int off = 32; off >= 1; off >>= 1) m = fmaxf(m, __shfl_xor(m, off));
    const float e = expf(s - m);
    float sum = e;
#pragma unroll
    for (int off = 32; off >= 1; off >>= 1) sum += __shfl_xor(sum, off);
    const float p = e / sum;

    // top-9 on biased raw score, lowest-index tie-break (matches lax.top_k)
    float wsel = s;
    float rv = 0.f;
    int ri = 0;
    float prev = 0.f, mingap = 1e30f;
#pragma unroll
    for (int r = 0; r < 9; ++r) {
      float v = wsel;
      int ii = lane;
#pragma unroll
      for (int off = 32; off >= 1; off >>= 1) {
        const float ov = __shfl_xor(v, off);
        const int oi = __shfl_xor(ii, off);
        if (ov > v || (ov == v && oi < ii)) { v = ov; ii = oi; }
      }
      if (r > 0) mingap = fminf(mingap, prev - v);
      prev = v;
      const float pw = __shfl(p, ii);
      if (lane == r) { rv = pw; ri = ii; }
      if (lane == ii) wsel = -1e30f;
    }

    bool toC = false;
    if (mingap < TAU && cap > 0) {
      int pos = 0;
      if (lane == 0) pos = atomicAdd(cnt, 1);
      pos = __shfl(pos, 0);
      if (pos < cap) {
        if (lane == 0) list[pos] = t;
        toC = true;  // recompute kernel produces all outputs for this token
      }
    }
    if (!toC) {
      S[base + lane] = p;
      if (lane < K) {
        wout[(size_t)t * K + lane] = rv;
        iout[(size_t)t * K + lane] = (float)ri;
        atomicAdd(&hist_s[ri], 1);
      }
    }
  }
  __syncthreads();
  if (tid < NE) atomicAdd(&hist[tid], hist_s[tid]);
}

// -------- f64 finalize for one token (lanes 0..63) ---------------
__device__ __forceinline__ void finalize_token_f64(
    int t, int lane, double s, float* __restrict__ S, float* __restrict__ wout,
    float* __restrict__ iout, int* __restrict__ hist, int K) {
  double m = s;
#pragma unroll
  for (int off = 32; off >= 1; off >>= 1) m = fmax(m, __shfl_xor(m, off));
  const double ex = exp(s - m);
  double sum = ex;
#pragma unroll
  for (int off = 32; off >= 1; off >>= 1) sum += __shfl_xor(sum, off);
  const double p = ex / sum;
  S[(size_t)t * NE + lane] = (float)p;
  double wsel = s;
  double rv = 0.0;
  int ri = 0;
  for (int r = 0; r < K; ++r) {
    double v = wsel;
    int ii = lane;
#pragma unroll
    for (int off = 32; off >= 1; off >>= 1) {
      const double ov = __shfl_xor(v, off);
      const int oi = __shfl_xor(ii, off);
      if (ov > v || (ov == v && oi < ii)) { v = ov; ii = oi; }
    }
    const double pw = __shfl(p, ii);
    if (lane == r) { rv = pw; ri = ii; }
    if (lane == ii) wsel = -1e300;
  }
  if (lane < K) {
    wout[(size_t)t * K + lane] = (float)rv;
    iout[(size_t)t * K + lane] = (float)ri;
    atomicAdd(&hist[ri], 1);
  }
}

// ------- Kernel 3: f64 recompute, 1 token/block, grid 512 -------------------
__global__ __launch_bounds__(256) void recompute_f64(
    const float* __restrict__ X, const float* __restrict__ W,
    const float* __restrict__ bias, float* __restrict__ S,
    float* __restrict__ wout, float* __restrict__ iout,
    const int* __restrict__ cnt, const int* __restrict__ list,
    int* __restrict__ hist, int H, int K, int cap) {
  if (cap <= 0) return;
  __shared__ float4 xs[1024];  // one token row (16 KB)
  __shared__ double red[256];
  const int tid = threadIdx.x;
  const int n = min(*cnt, cap);
  const int H4 = H >> 2;
  for (int idx = blockIdx.x; idx < n; idx += gridDim.x) {
    const int t = list[idx];
    __syncthreads();  // xs reuse from previous iteration
    const float4* xg = reinterpret_cast<const float4*>(X + (size_t)t * H);
    for (int i = tid; i < H4; i += 256) xs[i] = xg[i];
    __syncthreads();
    const int e = tid & 63, sl = tid >> 6;
    const int seg = H4 >> 2;  // 256 float4 per slice
    const float4* wr =
        reinterpret_cast<const float4*>(W + (size_t)e * H) + (size_t)sl * seg;
    const float4* xr = &xs[sl * seg];
    double a0 = 0.0, a1 = 0.0;  // split accumulators (break f64 dep chain)
    for (int k = 0; k < seg; k += 2) {
      const float4 w0 = wr[k], w1 = wr[k + 1];
      const float4 v0 = xr[k], v1 = xr[k + 1];
      a0 = fma((double)v0.x, (double)w0.x, a0);
      a0 = fma((double)v0.y, (double)w0.y, a0);
      a0 = fma((double)v0.z, (double)w0.z, a0);
      a0 = fma((double)v0.w, (double)w0.w, a0);
      a1 = fma((double)v1.x, (double)w1.x, a1);
      a1 = fma((double)v1.y, (double)w1.y, a1);
      a1 = fma((double)v1.z, (double)w1.z, a1);
      a1 = fma((double)v1.w, (double)w1.w, a1);
    }
    red[tid] = a0 + a1;
    __syncthreads();
    if (tid < 64) {
      const double s =
          red[e] + red[64 + e] + red[128 + e] + red[192 + e] + (double)bias[e];
      finalize_token_f64(t, e, s, S, wout, iout, hist, K);
    }
  }
}

// ------------- Kernel 4: bias update from integer histogram -----------------
__global__ void bias_update(const int* __restrict__ hist,
                            const float* __restrict__ bias,
                            float* __restrict__ bout, float tpe) {
  const int e = threadIdx.x;
  const float d = (float)hist[e] - tpe;
  const float sg = (d > 0.f) ? 1.f : ((d < 0.f) ? -1.f : 0.f);
  bout[e] = bias[e] + 0.01f * sg;
}

extern "C" void kernel_launch(void* const* d_in, const int* in_sizes, int n_in,
                              void* d_out, int out_size, void* d_ws, size_t ws_size,
                              hipStream_t stream) {
  const float* x = (const float*)d_in[0];
  const float* w = (const float*)d_in[1];
  const float* bias = (const float*)d_in[2];
  const int E = in_sizes[2];                       // 64
  const int H = in_sizes[1] / E;                   // 4096
  const long long N = (long long)in_sizes[0] / H;  // 32768 tokens
  const int K = (int)(((long long)out_size - N * E - E) / (2 * N));  // 8

  float* S = (float*)d_out;            // [N][E] probs (raw K-half0 first)
  float* wout = S + (size_t)N * E;     // [N][K]
  float* iout = wout + (size_t)N * K;  // [N][K] indices as float
  float* bout = iout + (size_t)N * K;  // [E]

  // ws: [0,4) cnt | [256,512) hist | Whi @4KB | Wlo | P2 @2MB (8MB) | list
  int* cnt = (int*)d_ws;
  int* hist = (int*)d_ws + 64;
  const size_t whalf = (size_t)E * H * sizeof(__bf16);  // 512 KB
  __bf16* Whi = (__bf16*)((char*)d_ws + 4096);
  __bf16* Wlo = (__bf16*)((char*)d_ws + 4096 + whalf);
  const size_t P2OFF = (size_t)2 << 20;
  float* P2 = (float*)((char*)d_ws + P2OFF);
  const size_t p2bytes = (size_t)N * NE * sizeof(float);  // 8 MB
  const size_t listoff = P2OFF + p2bytes;
  int* list = (int*)((char*)d_ws + listoff);
  int cap = 0;
  if (ws_size > listoff + 65536)
    cap = (int)min((size_t)32768, (ws_size - listoff) / 4);

  zero512<<<dim3(1), dim3(128), 0, stream>>>((int*)d_ws);
  const int n8 = E * H / 8;
  wconvert<<<dim3((n8 + 255) / 256), 256, 0, stream>>>(w, Whi, Wlo, n8, H);
  gemm_half<<<dim3((int)(N / 64), 2), 256, 0, stream>>>(x, Whi, Wlo, S, P2, H);
  finish<<<dim3((int)(N / 64)), 256, 0, stream>>>(P2, bias, S, wout, iout, cnt,
                                                  hist, list, cap, K);
  recompute_f64<<<dim3(512), 256, 0, stream>>>(x, w, bias, S, wout, iout, cnt,
                                               list, hist, H, K, cap);
  bias_update<<<dim3(1), dim3(E), 0, stream>>>(hist, bias, bout,
                                               (float)((double)N * K / E));
}

// Round 16
// 286.609 us; speedup vs baseline: 1.1747x; 1.0453x over previous
//
#include <hip/hip_runtime.h>

#define NE 64
#define TAU 1e-4f  // 4-term split-bf16 score sigma ~5e-6 -> 20-sigma guard
#define LSTR 68    // 68 mod 32 = 4 -> 2-way (free) LDS access in epilogue

typedef __bf16 bf16x8 __attribute__((ext_vector_type(8)));
typedef float f32x4 __attribute__((ext_vector_type(4)));

// split f32 -> bf16 hi + bf16 lo (hi RNE, lo = RNE(x - hi); x-hi exact in f32)
__device__ __forceinline__ void split8(const float4 a0, const float4 a1,
                                       bf16x8& hi, bf16x8& lo) {
  const float xs[8] = {a0.x, a0.y, a0.z, a0.w, a1.x, a1.y, a1.z, a1.w};
#pragma unroll
  for (int i = 0; i < 8; ++i) {
    const __bf16 h = (__bf16)xs[i];
    hi[i] = h;
    lo[i] = (__bf16)(xs[i] - (float)h);
  }
}

// async global->LDS, 16B/lane (for B staging; verified R13)
__device__ __forceinline__ void gld16(const void* g, void* l) {
  __builtin_amdgcn_global_load_lds(
      (const __attribute__((address_space(1))) void*)g,
      (__attribute__((address_space(3))) void*)l, 16, 0, 0);
}

// manual 16B global load -> VGPRs; asm volatile = cannot be sunk/hoisted
__device__ __forceinline__ void ld16(float4& d, const float* p) {
  asm volatile("global_load_dwordx4 %0, %1, off" : "=&v"(d) : "v"(p));
}

// ---- Kernel Z: zero cnt+hist ------------------------------------------------
__global__ void zero512(int* __restrict__ p) { p[threadIdx.x] = 0; }

// ---- Kernel 0: W -> bf16 hi/lo in FRAGMENT-MAJOR 32-k tiles (1 MB, once) ---
// elem(tt, j, lk, lr, kr) = tt*2048 + j*512 + (lk*16+lr)*8 + kr
// where W-row e = 16j+lr, k = 32tt + 8lk + kr. K-slice s (tt in [16s,16s+16))
// is 32768 contiguous elements (64 KB).
__global__ __launch_bounds__(256) void wconvert(const float* __restrict__ W,
                                                __bf16* __restrict__ Whi,
                                                __bf16* __restrict__ Wlo,
                                                int n8, int H) {
  const int i = blockIdx.x * 256 + threadIdx.x;
  if (i >= n8) return;
  const int hc = H >> 3;
  const int e = i / hc;
  const int k0 = (i - e * hc) * 8;
  const float4 a0 = *reinterpret_cast<const float4*>(W + (size_t)e * H + k0);
  const float4 a1 =
      *reinterpret_cast<const float4*>(W + (size_t)e * H + k0 + 4);
  bf16x8 hi, lo;
  split8(a0, a1, hi, lo);
  const int tt = k0 >> 5, lk = (k0 >> 3) & 3, j = e >> 4, lr = e & 15;
  const size_t off = (size_t)tt * 2048 + j * 512 + (lk * 16 + lr) * 8;
  *reinterpret_cast<bf16x8*>(Whi + off) = hi;
  *reinterpret_cast<bf16x8*>(Wlo + off) = lo;
}

// ------- Kernel 1: B-persistent LDS + within-macro asm A-pipeline -----------
// grid 256 (1 block/CU), 8 waves x 16 tokens = 128 tokens/block. acc persists
// across 8 K-slices. Per slice: stage B (128 KB hi+lo, gld16, drained) then
// 16 barrier-free k-steps in 4 macros: 8 asm A-loads up front, consumed at
// vmcnt(6/4/2/0)+sched_barrier. All asm dests dead by macro end -> no
// backedge liveness (the R14 hazard). B ds_reads lane-contiguous.
__global__ __launch_bounds__(512, 2) void gemm_fused(
    const float* __restrict__ X, const __bf16* __restrict__ Whi,
    const __bf16* __restrict__ Wlo, const float* __restrict__ bias,
    float* __restrict__ S, float* __restrict__ wout, float* __restrict__ iout,
    int* __restrict__ cnt, int* __restrict__ hist, int* __restrict__ list,
    int cap, int H, int K) {
  __shared__ alignas(16) char smem[131072];  // B-slice hi (64K) + lo (64K)
  __shared__ int hist_s[NE];
  const int tid = threadIdx.x;
  const int lane = tid & 63;
  const int wave = tid >> 6;  // 0..7
  if (tid < NE) hist_s[tid] = 0;
  const int lr = lane & 15;
  const int lk = lane >> 4;
  const int row0 = blockIdx.x * 128;

  __bf16* BH = (__bf16*)smem;  // [16 steps][4 j][64 lane][8]
  __bf16* BL = (__bf16*)(smem + 65536);

  const float* xp = X + (size_t)(row0 + 16 * wave + lr) * H + 8 * lk;

  f32x4 acc[4] = {};

#define STEP(RA, RB, STL, VM)                                                 \
  do {                                                                        \
    asm volatile("s_waitcnt vmcnt(" VM ")" ::: "memory");                     \
    __builtin_amdgcn_sched_barrier(0);                                        \
    bf16x8 Ahi, Alo;                                                          \
    split8(RA, RB, Ahi, Alo);                                                 \
    const __bf16* bhp = BH + (STL)*2048 + lane * 8;                           \
    const __bf16* blp = BL + (STL)*2048 + lane * 8;                           \
    bf16x8 BHf[4], BLf[4];                                                    \
    _Pragma("unroll") for (int j = 0; j < 4; ++j) {                           \
      BHf[j] = *reinterpret_cast<const bf16x8*>(bhp + j * 512);               \
      BLf[j] = *reinterpret_cast<const bf16x8*>(blp + j * 512);               \
    }                                                                         \
    _Pragma("unroll") for (int j = 0; j < 4; ++j) acc[j] =                    \
        __builtin_amdgcn_mfma_f32_16x16x32_bf16(Alo, BLf[j], acc[j], 0, 0, 0);\
    _Pragma("unroll") for (int j = 0; j < 4; ++j) acc[j] =                    \
        __builtin_amdgcn_mfma_f32_16x16x32_bf16(Alo, BHf[j], acc[j], 0, 0, 0);\
    _Pragma("unroll") for (int j = 0; j < 4; ++j) acc[j] =                    \
        __builtin_amdgcn_mfma_f32_16x16x32_bf16(Ahi, BLf[j], acc[j], 0, 0, 0);\
    _Pragma("unroll") for (int j = 0; j < 4; ++j) acc[j] =                    \
        __builtin_amdgcn_mfma_f32_16x16x32_bf16(Ahi, BHf[j], acc[j], 0, 0, 0);\
  } while (0)

  for (int s = 0; s < 8; ++s) {
    if (s) __syncthreads();  // all waves done reading previous slice
    // ---- stage B slice s: 64 KB hi + 64 KB lo via gld16 (proven R13) ----
    const float* sh =
        (const float*)(Whi + (size_t)s * 32768 + wave * 4096 + lane * 8);
    const float* sl =
        (const float*)(Wlo + (size_t)s * 32768 + wave * 4096 + lane * 8);
#pragma unroll
    for (int i = 0; i < 8; ++i) {
      gld16(sh + i * 256, BH + wave * 4096 + i * 512);
      gld16(sl + i * 256, BL + wave * 4096 + i * 512);
    }
    asm volatile("s_waitcnt vmcnt(0)" ::: "memory");
    __syncthreads();  // slice resident for all waves

    // ---- 16 barrier-free k-steps in 4 macros of 4 ----
    for (int mb = 0; mb < 4; ++mb) {
      const int t0 = s * 16 + mb * 4;  // global 32-k step index
      float4 a0, a1, a2, a3, a4, a5, a6, a7;
      ld16(a0, xp + 32 * (size_t)t0);
      ld16(a1, xp + 32 * (size_t)t0 + 4);
      ld16(a2, xp + 32 * (size_t)(t0 + 1));
      ld16(a3, xp + 32 * (size_t)(t0 + 1) + 4);
      ld16(a4, xp + 32 * (size_t)(t0 + 2));
      ld16(a5, xp + 32 * (size_t)(t0 + 2) + 4);
      ld16(a6, xp + 32 * (size_t)(t0 + 3));
      ld16(a7, xp + 32 * (size_t)(t0 + 3) + 4);
      STEP(a0, a1, mb * 4 + 0, "6");
      STEP(a2, a3, mb * 4 + 1, "4");
      STEP(a4, a5, mb * 4 + 2, "2");
      STEP(a6, a7, mb * 4 + 3, "0");
    }
  }
#undef STEP

  // ---- epilogue: transpose scores to token-major LDS (aliases smem) ----
  __syncthreads();
  float* Ls = (float*)smem;  // 128*68*4 = 34816 B <= 131072
#pragma unroll
  for (int j = 0; j < 4; ++j)
#pragma unroll
    for (int r = 0; r < 4; ++r)
      Ls[(16 * wave + 4 * lk + r) * LSTR + 16 * j + lr] = acc[j][r];
  __syncthreads();

  const float bv = bias[lane];
  for (int tt = 0; tt < 16; ++tt) {
    const int tl = wave * 16 + tt;
    const int t = row0 + tl;
    const float s = Ls[tl * LSTR + lane] + bv;

    float m = s;
#pragma unroll
    for (int off = 32; off >= 1; off >>= 1) m = fmaxf(m, __shfl_xor(m, off));
    const float e = expf(s - m);
    float sum = e;
#pragma unroll
    for (int off = 32; off >= 1; off >>= 1) sum += __shfl_xor(sum, off);
    const float p = e / sum;

    // top-9 on biased raw score, lowest-index tie-break (matches lax.top_k)
    float wsel = s;
    float rv = 0.f;
    int ri = 0;
    float prev = 0.f, mingap = 1e30f;
#pragma unroll
    for (int r = 0; r < 9; ++r) {
      float v = wsel;
      int ii = lane;
#pragma unroll
      for (int off = 32; off >= 1; off >>= 1) {
        const float ov = __shfl_xor(v, off);
        const int oi = __shfl_xor(ii, off);
        if (ov > v || (ov == v && oi < ii)) { v = ov; ii = oi; }
      }
      if (r > 0) mingap = fminf(mingap, prev - v);
      prev = v;
      const float pw = __shfl(p, ii);
      if (lane == r) { rv = pw; ri = ii; }
      if (lane == ii) wsel = -1e30f;
    }

    bool toC = false;
    if (mingap < TAU && cap > 0) {
      int pos = 0;
      if (lane == 0) pos = atomicAdd(cnt, 1);
      pos = __shfl(pos, 0);
      if (pos < cap) {
        if (lane == 0) list[pos] = t;
        toC = true;  // recompute kernel produces all outputs for this token
      }
    }
    if (!toC) {
      S[(size_t)t * NE + lane] = p;
      if (lane < K) {
        wout[(size_t)t * K + lane] = rv;
        iout[(size_t)t * K + lane] = (float)ri;
        atomicAdd(&hist_s[ri], 1);
      }
    }
  }
  __syncthreads();
  if (tid < NE) atomicAdd(&hist[tid], hist_s[tid]);
}

// -------- f64 finalize for one token (lanes 0..63) ---------------
__device__ __forceinline__ void finalize_token_f64(
    int t, int lane, double s, float* __restrict__ S, float* __restrict__ wout,
    float* __restrict__ iout, int* __restrict__ hist, int K) {
  double m = s;
#pragma unroll
  for (int off = 32; off >= 1; off >>= 1) m = fmax(m, __shfl_xor(m, off));
  const double ex = exp(s - m);
  double sum = ex;
#pragma unroll
  for (int off = 32; off >= 1; off >>= 1) sum += __shfl_xor(sum, off);
  const double p = ex / sum;
  S[(size_t)t * NE + lane] = (float)p;
  double wsel = s;
  double rv = 0.0;
  int ri = 0;
  for (int r = 0; r < K; ++r) {
    double v = wsel;
    int ii = lane;
#pragma unroll
    for (int off = 32; off >= 1; off >>= 1) {
      const double ov = __shfl_xor(v, off);
      const int oi = __shfl_xor(ii, off);
      if (ov > v || (ov == v && oi < ii)) { v = ov; ii = oi; }
    }
    const double pw = __shfl(p, ii);
    if (lane == r) { rv = pw; ri = ii; }
    if (lane == ii) wsel = -1e300;
  }
  if (lane < K) {
    wout[(size_t)t * K + lane] = (float)rv;
    iout[(size_t)t * K + lane] = (float)ri;
    atomicAdd(&hist[ri], 1);
  }
}

// ------- Kernel 2: f64 recompute, 1 token/block, grid 512 -------------------
__global__ __launch_bounds__(256) void recompute_f64(
    const float* __restrict__ X, const float* __restrict__ W,
    const float* __restrict__ bias, float* __restrict__ S,
    float* __restrict__ wout, float* __restrict__ iout,
    const int* __restrict__ cnt, const int* __restrict__ list,
    int* __restrict__ hist, int H, int K, int cap) {
  if (cap <= 0) return;
  __shared__ float4 xs[1024];  // one token row (16 KB)
  __shared__ double red[256];
  const int tid = threadIdx.x;
  const int n = min(*cnt, cap);
  const int H4 = H >> 2;
  for (int idx = blockIdx.x; idx < n; idx += gridDim.x) {
    const int t = list[idx];
    __syncthreads();  // xs reuse from previous iteration
    const float4* xg = reinterpret_cast<const float4*>(X + (size_t)t * H);
    for (int i = tid; i < H4; i += 256) xs[i] = xg[i];
    __syncthreads();
    const int e = tid & 63, sl = tid >> 6;
    const int seg = H4 >> 2;  // 256 float4 per slice
    const float4* wr =
        reinterpret_cast<const float4*>(W + (size_t)e * H) + (size_t)sl * seg;
    const float4* xr = &xs[sl * seg];
    double a0 = 0.0, a1 = 0.0;  // split accumulators (break f64 dep chain)
    for (int k = 0; k < seg; k += 2) {
      const float4 w0 = wr[k], w1 = wr[k + 1];
      const float4 v0 = xr[k], v1 = xr[k + 1];
      a0 = fma((double)v0.x, (double)w0.x, a0);
      a0 = fma((double)v0.y, (double)w0.y, a0);
      a0 = fma((double)v0.z, (double)w0.z, a0);
      a0 = fma((double)v0.w, (double)w0.w, a0);
      a1 = fma((double)v1.x, (double)w1.x, a1);
      a1 = fma((double)v1.y, (double)w1.y, a1);
      a1 = fma((double)v1.z, (double)w1.z, a1);
      a1 = fma((double)v1.w, (double)w1.w, a1);
    }
    red[tid] = a0 + a1;
    __syncthreads();
    if (tid < 64) {
      const double s =
          red[e] + red[64 + e] + red[128 + e] + red[192 + e] + (double)bias[e];
      finalize_token_f64(t, e, s, S, wout, iout, hist, K);
    }
  }
}

// ------------- Kernel 3: bias update from integer histogram -----------------
__global__ void bias_update(const int* __restrict__ hist,
                            const float* __restrict__ bias,
                            float* __restrict__ bout, float tpe) {
  const int e = threadIdx.x;
  const float d = (float)hist[e] - tpe;
  const float sg = (d > 0.f) ? 1.f : ((d < 0.f) ? -1.f : 0.f);
  bout[e] = bias[e] + 0.01f * sg;
}

extern "C" void kernel_launch(void* const* d_in, const int* in_sizes, int n_in,
                              void* d_out, int out_size, void* d_ws, size_t ws_size,
                              hipStream_t stream) {
  const float* x = (const float*)d_in[0];
  const float* w = (const float*)d_in[1];
  const float* bias = (const float*)d_in[2];
  const int E = in_sizes[2];                       // 64
  const int H = in_sizes[1] / E;                   // 4096
  const long long N = (long long)in_sizes[0] / H;  // 32768 tokens
  const int K = (int)(((long long)out_size - N * E - E) / (2 * N));  // 8

  float* S = (float*)d_out;            // [N][E] probs
  float* wout = S + (size_t)N * E;     // [N][K]
  float* iout = wout + (size_t)N * K;  // [N][K] indices as float
  float* bout = iout + (size_t)N * K;  // [E]

  // ws: [0,4) cnt | [256,512) hist | Whi @4KB (512KB) | Wlo | list after
  int* cnt = (int*)d_ws;
  int* hist = (int*)d_ws + 64;
  const size_t whalf = (size_t)E * H * sizeof(__bf16);  // 512 KB
  __bf16* Whi = (__bf16*)((char*)d_ws + 4096);
  __bf16* Wlo = (__bf16*)((char*)d_ws + 4096 + whalf);
  const size_t listoff = 4096 + 2 * whalf;
  int* list = (int*)((char*)d_ws + listoff);
  int cap = 0;
  if (ws_size > listoff + 65536)
    cap = (int)min((size_t)32768, (ws_size - listoff) / 4);

  zero512<<<dim3(1), dim3(128), 0, stream>>>((int*)d_ws);
  const int n8 = E * H / 8;
  wconvert<<<dim3((n8 + 255) / 256), 256, 0, stream>>>(w, Whi, Wlo, n8, H);
  gemm_fused<<<dim3((int)(N / 128)), 512, 0, stream>>>(
      x, Whi, Wlo, bias, S, wout, iout, cnt, hist, list, cap, H, K);
  recompute_f64<<<dim3(512), 256, 0, stream>>>(x, w, bias, S, wout, iout, cnt,
                                               list, hist, H, K, cap);
  bias_update<<<dim3(1), dim3(E), 0, stream>>>(hist, bias, bout,
                                               (float)((double)N * K / E));
}

// Round 17
// 273.266 us; speedup vs baseline: 1.2320x; 1.0488x over previous
//
#include <hip/hip_runtime.h>

#define NE 64
#define TAU 1e-4f  // 4-term split-bf16 score sigma ~5e-6 -> 20-sigma guard
#define LSTR 68    // 68 mod 32 = 4 -> 2-way (free) LDS access in epilogue

typedef __bf16 bf16x8 __attribute__((ext_vector_type(8)));
typedef float f32x4 __attribute__((ext_vector_type(4)));

// split f32 -> bf16 hi + bf16 lo (hi RNE, lo = RNE(x - hi); x-hi exact in f32)
__device__ __forceinline__ void split8(const float4 a0, const float4 a1,
                                       bf16x8& hi, bf16x8& lo) {
  const float xs[8] = {a0.x, a0.y, a0.z, a0.w, a1.x, a1.y, a1.z, a1.w};
#pragma unroll
  for (int i = 0; i < 8; ++i) {
    const __bf16 h = (__bf16)xs[i];
    hi[i] = h;
    lo[i] = (__bf16)(xs[i] - (float)h);
  }
}

// async global->LDS, 16B/lane; LDS dest = wave-uniform base, HW adds lane*16
__device__ __forceinline__ void gld16(const void* g, void* l) {
  __builtin_amdgcn_global_load_lds(
      (const __attribute__((address_space(1))) void*)g,
      (__attribute__((address_space(3))) void*)l, 16, 0, 0);
}

// ---- Kernel Z: zero cnt+hist ------------------------------------------------
__global__ void zero512(int* __restrict__ p) { p[threadIdx.x] = 0; }

// ---- Kernel 0: W -> bf16 hi/lo in FRAGMENT-MAJOR 32-k tiles (1 MB, once) ---
// elem(tt, j, lk, lr, kr) = tt*2048 + j*512 + (lk*16+lr)*8 + kr
// where W-row e = 16j+lr, k = 32tt + 8lk + kr.
__global__ __launch_bounds__(256) void wconvert(const float* __restrict__ W,
                                                __bf16* __restrict__ Whi,
                                                __bf16* __restrict__ Wlo,
                                                int n8, int H) {
  const int i = blockIdx.x * 256 + threadIdx.x;
  if (i >= n8) return;
  const int hc = H >> 3;
  const int e = i / hc;
  const int k0 = (i - e * hc) * 8;
  const float4 a0 = *reinterpret_cast<const float4*>(W + (size_t)e * H + k0);
  const float4 a1 =
      *reinterpret_cast<const float4*>(W + (size_t)e * H + k0 + 4);
  bf16x8 hi, lo;
  split8(a0, a1, hi, lo);
  const int tt = k0 >> 5, lk = (k0 >> 3) & 3, j = e >> 4, lr = e & 15;
  const size_t off = (size_t)tt * 2048 + j * 512 + (lk * 16 + lr) * 8;
  *reinterpret_cast<bf16x8*>(Whi + off) = hi;
  *reinterpret_cast<bf16x8*>(Wlo + off) = lo;
}

// ------- Kernel 1: ROW-CONTIGUOUS-A split-bf16 MFMA GEMM --------------------
// grid 256 (1 block/CU), 8 waves x 16 tokens = 128 tokens/block; acc persists.
// Per 128-k slice: A staged as 16 rows x 512 B CONTIGUOUS runs (8 gld16/wave;
// lanes 0-31 row 2i, 32-63 row 2i+1; 16B chunks XOR-preswizzled WITHIN the
// 512B run -> same DRAM page, bank-spread LDS reads). B fragment-major
// (4 gld16/wave). Then 4 barrier-free 32-k steps: A 2x ds_read_b128 swizzled
// + B 8x lane-contiguous + 16 MFMA. DRAM sees 512B/activation instead of 64B.
__global__ __launch_bounds__(512, 1) void gemm_fused(
    const float* __restrict__ X, const __bf16* __restrict__ Whi,
    const __bf16* __restrict__ Wlo, const float* __restrict__ bias,
    float* __restrict__ S, float* __restrict__ wout, float* __restrict__ iout,
    int* __restrict__ cnt, int* __restrict__ hist, int* __restrict__ list,
    int cap, int H, int K) {
  __shared__ alignas(16) char smem[98304];  // A 64K | BH 16K | BL 16K
  __shared__ int hist_s[NE];
  const int tid = threadIdx.x;
  const int lane = tid & 63;
  const int wave = tid >> 6;  // 0..7
  if (tid < NE) hist_s[tid] = 0;
  const int lr = lane & 15;
  const int lk = lane >> 4;
  const int row0 = blockIdx.x * 128;

  float* A0 = (float*)smem;                 // [wave][row 0..15][32 chunks^swz]
  __bf16* BH = (__bf16*)(smem + 65536);     // [4 ts][4 j][64 lane][8]
  __bf16* BL = (__bf16*)(smem + 81920);

  // A staging sources: instr i, lane -> row r = 2i + (lane>>5), chunk slot
  // jj = lane&31 holds global chunk jj ^ (r&7) of this row's 512B slice-run.
  const int jj = lane & 31;
  const int half = lane >> 5;
  const float* srcA[8];
#pragma unroll
  for (int i = 0; i < 8; ++i) {
    const int r = 2 * i + half;
    srcA[i] = X + (size_t)(row0 + 16 * wave + r) * H + ((jj ^ (r & 7)) << 2);
  }
  const __bf16* srcBh = Whi + wave * 1024 + lane * 8;
  const __bf16* srcBl = Wlo + wave * 1024 + lane * 8;

  f32x4 acc[4] = {};
  const int NSL = H >> 7;  // 32 slices of 128 k

  for (int s = 0; s < NSL; ++s) {
    if (s) __syncthreads();  // all waves done reading previous slice
    // ---- stage A (8 gld16: 16 rows x 512B contiguous) + B (4 gld16) ----
#pragma unroll
    for (int i = 0; i < 8; ++i)
      gld16(srcA[i] + s * 128, A0 + wave * 2048 + i * 256);
    gld16(srcBh + (size_t)s * 8192, BH + wave * 1024);
    gld16(srcBh + (size_t)s * 8192 + 512, BH + wave * 1024 + 512);
    gld16(srcBl + (size_t)s * 8192, BL + wave * 1024);
    gld16(srcBl + (size_t)s * 8192 + 512, BL + wave * 1024 + 512);
    asm volatile("s_waitcnt vmcnt(0)" ::: "memory");
    __syncthreads();  // slice resident for all waves

    // ---- 4 barrier-free 32-k steps ----
    const float* Aw = A0 + wave * 2048 + lr * 128;
#pragma unroll
    for (int ts = 0; ts < 4; ++ts) {
      const int c0 = (ts << 3) | (lk << 1);
      const float4 f0 =
          *reinterpret_cast<const float4*>(Aw + ((c0 ^ (lr & 7)) << 2));
      const float4 f1 =
          *reinterpret_cast<const float4*>(Aw + (((c0 + 1) ^ (lr & 7)) << 2));
      bf16x8 Ahi, Alo;
      split8(f0, f1, Ahi, Alo);
      const __bf16* bhp = BH + ts * 2048 + lane * 8;
      const __bf16* blp = BL + ts * 2048 + lane * 8;
      bf16x8 BHf[4], BLf[4];
#pragma unroll
      for (int j = 0; j < 4; ++j) {
        BHf[j] = *reinterpret_cast<const bf16x8*>(bhp + j * 512);
        BLf[j] = *reinterpret_cast<const bf16x8*>(blp + j * 512);
      }
      // term-major; per-acc order LL, LH, HL, HH (identical to R10-R16)
#pragma unroll
      for (int j = 0; j < 4; ++j)
        acc[j] = __builtin_amdgcn_mfma_f32_16x16x32_bf16(Alo, BLf[j], acc[j], 0, 0, 0);
#pragma unroll
      for (int j = 0; j < 4; ++j)
        acc[j] = __builtin_amdgcn_mfma_f32_16x16x32_bf16(Alo, BHf[j], acc[j], 0, 0, 0);
#pragma unroll
      for (int j = 0; j < 4; ++j)
        acc[j] = __builtin_amdgcn_mfma_f32_16x16x32_bf16(Ahi, BLf[j], acc[j], 0, 0, 0);
#pragma unroll
      for (int j = 0; j < 4; ++j)
        acc[j] = __builtin_amdgcn_mfma_f32_16x16x32_bf16(Ahi, BHf[j], acc[j], 0, 0, 0);
    }
  }

  // ---- epilogue: transpose scores to token-major LDS (aliases smem) ----
  __syncthreads();
  float* Ls = (float*)smem;  // 128*68*4 = 34816 B <= 98304
#pragma unroll
  for (int j = 0; j < 4; ++j)
#pragma unroll
    for (int r = 0; r < 4; ++r)
      Ls[(16 * wave + 4 * lk + r) * LSTR + 16 * j + lr] = acc[j][r];
  __syncthreads();

  const float bv = bias[lane];
  for (int tt = 0; tt < 16; ++tt) {
    const int tl = wave * 16 + tt;
    const int t = row0 + tl;
    const float s = Ls[tl * LSTR + lane] + bv;

    float m = s;
#pragma unroll
    for (int off = 32; off >= 1; off >>= 1) m = fmaxf(m, __shfl_xor(m, off));
    const float e = expf(s - m);
    float sum = e;
#pragma unroll
    for (int off = 32; off >= 1; off >>= 1) sum += __shfl_xor(sum, off);
    const float p = e / sum;

    // top-9 on biased raw score, lowest-index tie-break (matches lax.top_k)
    float wsel = s;
    float rv = 0.f;
    int ri = 0;
    float prev = 0.f, mingap = 1e30f;
#pragma unroll
    for (int r = 0; r < 9; ++r) {
      float v = wsel;
      int ii = lane;
#pragma unroll
      for (int off = 32; off >= 1; off >>= 1) {
        const float ov = __shfl_xor(v, off);
        const int oi = __shfl_xor(ii, off);
        if (ov > v || (ov == v && oi < ii)) { v = ov; ii = oi; }
      }
      if (r > 0) mingap = fminf(mingap, prev - v);
      prev = v;
      const float pw = __shfl(p, ii);
      if (lane == r) { rv = pw; ri = ii; }
      if (lane == ii) wsel = -1e30f;
    }

    bool toC = false;
    if (mingap < TAU && cap > 0) {
      int pos = 0;
      if (lane == 0) pos = atomicAdd(cnt, 1);
      pos = __shfl(pos, 0);
      if (pos < cap) {
        if (lane == 0) list[pos] = t;
        toC = true;  // recompute kernel produces all outputs for this token
      }
    }
    if (!toC) {
      S[(size_t)t * NE + lane] = p;
      if (lane < K) {
        wout[(size_t)t * K + lane] = rv;
        iout[(size_t)t * K + lane] = (float)ri;
        atomicAdd(&hist_s[ri], 1);
      }
    }
  }
  __syncthreads();
  if (tid < NE) atomicAdd(&hist[tid], hist_s[tid]);
}

// -------- f64 finalize for one token (lanes 0..63) ---------------
__device__ __forceinline__ void finalize_token_f64(
    int t, int lane, double s, float* __restrict__ S, float* __restrict__ wout,
    float* __restrict__ iout, int* __restrict__ hist, int K) {
  double m = s;
#pragma unroll
  for (int off = 32; off >= 1; off >>= 1) m = fmax(m, __shfl_xor(m, off));
  const double ex = exp(s - m);
  double sum = ex;
#pragma unroll
  for (int off = 32; off >= 1; off >>= 1) sum += __shfl_xor(sum, off);
  const double p = ex / sum;
  S[(size_t)t * NE + lane] = (float)p;
  double wsel = s;
  double rv = 0.0;
  int ri = 0;
  for (int r = 0; r < K; ++r) {
    double v = wsel;
    int ii = lane;
#pragma unroll
    for (int off = 32; off >= 1; off >>= 1) {
      const double ov = __shfl_xor(v, off);
      const int oi = __shfl_xor(ii, off);
      if (ov > v || (ov == v && oi < ii)) { v = ov; ii = oi; }
    }
    const double pw = __shfl(p, ii);
    if (lane == r) { rv = pw; ri = ii; }
    if (lane == ii) wsel = -1e300;
  }
  if (lane < K) {
    wout[(size_t)t * K + lane] = (float)rv;
    iout[(size_t)t * K + lane] = (float)ri;
    atomicAdd(&hist[ri], 1);
  }
}

// ------- Kernel 2: f64 recompute, 1 token/block, grid 512 -------------------
__global__ __launch_bounds__(256) void recompute_f64(
    const float* __restrict__ X, const float* __restrict__ W,
    const float* __restrict__ bias, float* __restrict__ S,
    float* __restrict__ wout, float* __restrict__ iout,
    const int* __restrict__ cnt, const int* __restrict__ list,
    int* __restrict__ hist, int H, int K, int cap) {
  if (cap <= 0) return;
  __shared__ float4 xs[1024];  // one token row (16 KB)
  __shared__ double red[256];
  const int tid = threadIdx.x;
  const int n = min(*cnt, cap);
  const int H4 = H >> 2;
  for (int idx = blockIdx.x; idx < n; idx += gridDim.x) {
    const int t = list[idx];
    __syncthreads();  // xs reuse from previous iteration
    const float4* xg = reinterpret_cast<const float4*>(X + (size_t)t * H);
    for (int i = tid; i < H4; i += 256) xs[i] = xg[i];
    __syncthreads();
    const int e = tid & 63, sl = tid >> 6;
    const int seg = H4 >> 2;  // 256 float4 per slice
    const float4* wr =
        reinterpret_cast<const float4*>(W + (size_t)e * H) + (size_t)sl * seg;
    const float4* xr = &xs[sl * seg];
    double a0 = 0.0, a1 = 0.0;  // split accumulators (break f64 dep chain)
    for (int k = 0; k < seg; k += 2) {
      const float4 w0 = wr[k], w1 = wr[k + 1];
      const float4 v0 = xr[k], v1 = xr[k + 1];
      a0 = fma((double)v0.x, (double)w0.x, a0);
      a0 = fma((double)v0.y, (double)w0.y, a0);
      a0 = fma((double)v0.z, (double)w0.z, a0);
      a0 = fma((double)v0.w, (double)w0.w, a0);
      a1 = fma((double)v1.x, (double)w1.x, a1);
      a1 = fma((double)v1.y, (double)w1.y, a1);
      a1 = fma((double)v1.z, (double)w1.z, a1);
      a1 = fma((double)v1.w, (double)w1.w, a1);
    }
    red[tid] = a0 + a1;
    __syncthreads();
    if (tid < 64) {
      const double s =
          red[e] + red[64 + e] + red[128 + e] + red[192 + e] + (double)bias[e];
      finalize_token_f64(t, e, s, S, wout, iout, hist, K);
    }
  }
}

// ------------- Kernel 3: bias update from integer histogram -----------------
__global__ void bias_update(const int* __restrict__ hist,
                            const float* __restrict__ bias,
                            float* __restrict__ bout, float tpe) {
  const int e = threadIdx.x;
  const float d = (float)hist[e] - tpe;
  const float sg = (d > 0.f) ? 1.f : ((d < 0.f) ? -1.f : 0.f);
  bout[e] = bias[e] + 0.01f * sg;
}

extern "C" void kernel_launch(void* const* d_in, const int* in_sizes, int n_in,
                              void* d_out, int out_size, void* d_ws, size_t ws_size,
                              hipStream_t stream) {
  const float* x = (const float*)d_in[0];
  const float* w = (const float*)d_in[1];
  const float* bias = (const float*)d_in[2];
  const int E = in_sizes[2];                       // 64
  const int H = in_sizes[1] / E;                   // 4096
  const long long N = (long long)in_sizes[0] / H;  // 32768 tokens
  const int K = (int)(((long long)out_size - N * E - E) / (2 * N));  // 8

  float* S = (float*)d_out;            // [N][E] probs
  float* wout = S + (size_t)N * E;     // [N][K]
  float* iout = wout + (size_t)N * K;  // [N][K] indices as float
  float* bout = iout + (size_t)N * K;  // [E]

  // ws: [0,4) cnt | [256,512) hist | Whi @4KB (512KB) | Wlo | list after
  int* cnt = (int*)d_ws;
  int* hist = (int*)d_ws + 64;
  const size_t whalf = (size_t)E * H * sizeof(__bf16);  // 512 KB
  __bf16* Whi = (__bf16*)((char*)d_ws + 4096);
  __bf16* Wlo = (__bf16*)((char*)d_ws + 4096 + whalf);
  const size_t listoff = 4096 + 2 * whalf;
  int* list = (int*)((char*)d_ws + listoff);
  int cap = 0;
  if (ws_size > listoff + 65536)
    cap = (int)min((size_t)32768, (ws_size - listoff) / 4);

  zero512<<<dim3(1), dim3(128), 0, stream>>>((int*)d_ws);
  const int n8 = E * H / 8;
  wconvert<<<dim3((n8 + 255) / 256), 256, 0, stream>>>(w, Whi, Wlo, n8, H);
  gemm_fused<<<dim3((int)(N / 128)), 512, 0, stream>>>(
      x, Whi, Wlo, bias, S, wout, iout, cnt, hist, list, cap, H, K);
  recompute_f64<<<dim3(512), 256, 0, stream>>>(x, w, bias, S, wout, iout, cnt,
                                               list, hist, H, K, cap);
  bias_update<<<dim3(1), dim3(E), 0, stream>>>(hist, bias, bout,
                                               (float)((double)N * K / E));
}

// Round 18
// 261.548 us; speedup vs baseline: 1.2872x; 1.0448x over previous
//
#include <hip/hip_runtime.h>

#define NE 64
#define TAU 1e-4f  // 4-term split-bf16 score sigma ~5e-6 -> 20-sigma guard
#define LSTR 68    // 68 mod 32 = 4 -> 2-way (free) LDS access in epilogue

typedef __bf16 bf16x8 __attribute__((ext_vector_type(8)));
typedef float f32x4 __attribute__((ext_vector_type(4)));

// split f32 -> bf16 hi + bf16 lo (hi RNE, lo = RNE(x - hi); x-hi exact in f32)
__device__ __forceinline__ void split8(const float4 a0, const float4 a1,
                                       bf16x8& hi, bf16x8& lo) {
  const float xs[8] = {a0.x, a0.y, a0.z, a0.w, a1.x, a1.y, a1.z, a1.w};
#pragma unroll
  for (int i = 0; i < 8; ++i) {
    const __bf16 h = (__bf16)xs[i];
    hi[i] = h;
    lo[i] = (__bf16)(xs[i] - (float)h);
  }
}

// async global->LDS, 16B/lane; LDS dest = wave-uniform base, HW adds lane*16
__device__ __forceinline__ void gld16(const void* g, void* l) {
  __builtin_amdgcn_global_load_lds(
      (const __attribute__((address_space(1))) void*)g,
      (__attribute__((address_space(3))) void*)l, 16, 0, 0);
}

// ---- Kernel Z: zero cnt+hist ------------------------------------------------
__global__ void zero512(int* __restrict__ p) { p[threadIdx.x] = 0; }

// ---- Kernel 0: W -> bf16 hi/lo in FRAGMENT-MAJOR 32-k tiles (1 MB, once) ---
// elem(tt, j, lk, lr, kr) = tt*2048 + j*512 + (lk*16+lr)*8 + kr
// where W-row e = 16j+lr, k = 32tt + 8lk + kr.
__global__ __launch_bounds__(256) void wconvert(const float* __restrict__ W,
                                                __bf16* __restrict__ Whi,
                                                __bf16* __restrict__ Wlo,
                                                int n8, int H) {
  const int i = blockIdx.x * 256 + threadIdx.x;
  if (i >= n8) return;
  const int hc = H >> 3;
  const int e = i / hc;
  const int k0 = (i - e * hc) * 8;
  const float4 a0 = *reinterpret_cast<const float4*>(W + (size_t)e * H + k0);
  const float4 a1 =
      *reinterpret_cast<const float4*>(W + (size_t)e * H + k0 + 4);
  bf16x8 hi, lo;
  split8(a0, a1, hi, lo);
  const int tt = k0 >> 5, lk = (k0 >> 3) & 3, j = e >> 4, lr = e & 15;
  const size_t off = (size_t)tt * 2048 + j * 512 + (lk * 16 + lr) * 8;
  *reinterpret_cast<bf16x8*>(Whi + off) = hi;
  *reinterpret_cast<bf16x8*>(Wlo + off) = lo;
}

// ------- Kernel 1: row-contiguous-A GEMM, 2 blocks/CU phase overlap ---------
// 4 waves x 16 tokens = 64 tokens/block; grid N/64 = 512 = 2 blocks/CU.
// While one block drains its slice stage, the co-resident block computes
// (m114 wave-level overlap) -- no compiler pipelining needed.
// Per 128-k slice: A staged as 16 rows x 512B contiguous runs per wave
// (8 gld16, 16B chunks XOR-preswizzled within the run); B fragment-major
// (8 gld16/wave). Then 4 barrier-free 32-k steps: 2 A + 8 B ds_read_b128
// + 16 MFMA (4-term split-bf16; order identical to R10-R17).
__global__ __launch_bounds__(256, 2) void gemm_fused(
    const float* __restrict__ X, const __bf16* __restrict__ Whi,
    const __bf16* __restrict__ Wlo, const float* __restrict__ bias,
    float* __restrict__ S, float* __restrict__ wout, float* __restrict__ iout,
    int* __restrict__ cnt, int* __restrict__ hist, int* __restrict__ list,
    int cap, int H, int K) {
  __shared__ alignas(16) char smem[65536];  // A 32K | BH 16K | BL 16K
  __shared__ int hist_s[NE];
  const int tid = threadIdx.x;
  const int lane = tid & 63;
  const int wave = tid >> 6;  // 0..3
  if (tid < NE) hist_s[tid] = 0;
  const int lr = lane & 15;
  const int lk = lane >> 4;
  const int row0 = blockIdx.x * 64;

  float* A0 = (float*)smem;              // [wave][16 rows][32 chunks ^ swz]
  __bf16* BH = (__bf16*)(smem + 32768);  // [4 ts][4 j][64 lane][8]
  __bf16* BL = (__bf16*)(smem + 49152);

  // A staging sources: instr i, lane -> row r = 2i + (lane>>5), chunk slot
  // jj = lane&31 holds global chunk jj ^ (r&7) of this row's 512B slice-run.
  const int jj = lane & 31;
  const int half = lane >> 5;
  const float* srcA[8];
#pragma unroll
  for (int i = 0; i < 8; ++i) {
    const int r = 2 * i + half;
    srcA[i] = X + (size_t)(row0 + 16 * wave + r) * H + ((jj ^ (r & 7)) << 2);
  }
  // B staging: per slice, wave w stages tt-block w (2048 elems = 4 gld16 each
  // of hi and lo).
  const __bf16* srcBh = Whi + wave * 2048 + lane * 8;
  const __bf16* srcBl = Wlo + wave * 2048 + lane * 8;

  f32x4 acc[4] = {};
  const int NSL = H >> 7;  // 32 slices of 128 k

  for (int s = 0; s < NSL; ++s) {
    if (s) __syncthreads();  // all waves done reading previous slice
    // ---- stage A (8 gld16) + B (8 gld16) for slice s ----
#pragma unroll
    for (int i = 0; i < 8; ++i)
      gld16(srcA[i] + s * 128, A0 + wave * 2048 + i * 256);
#pragma unroll
    for (int i = 0; i < 4; ++i) {
      gld16(srcBh + (size_t)s * 8192 + i * 512, BH + wave * 2048 + i * 512);
      gld16(srcBl + (size_t)s * 8192 + i * 512, BL + wave * 2048 + i * 512);
    }
    asm volatile("s_waitcnt vmcnt(0)" ::: "memory");
    __syncthreads();  // slice resident for all waves

    // ---- 4 barrier-free 32-k steps ----
    const float* Aw = A0 + wave * 2048 + lr * 128;
#pragma unroll
    for (int ts = 0; ts < 4; ++ts) {
      const int c0 = (ts << 3) | (lk << 1);
      const float4 f0 =
          *reinterpret_cast<const float4*>(Aw + ((c0 ^ (lr & 7)) << 2));
      const float4 f1 =
          *reinterpret_cast<const float4*>(Aw + (((c0 + 1) ^ (lr & 7)) << 2));
      bf16x8 Ahi, Alo;
      split8(f0, f1, Ahi, Alo);
      const __bf16* bhp = BH + ts * 2048 + lane * 8;
      const __bf16* blp = BL + ts * 2048 + lane * 8;
      bf16x8 BHf[4], BLf[4];
#pragma unroll
      for (int j = 0; j < 4; ++j) {
        BHf[j] = *reinterpret_cast<const bf16x8*>(bhp + j * 512);
        BLf[j] = *reinterpret_cast<const bf16x8*>(blp + j * 512);
      }
      // term-major; per-acc order LL, LH, HL, HH (identical to R10-R17)
#pragma unroll
      for (int j = 0; j < 4; ++j)
        acc[j] = __builtin_amdgcn_mfma_f32_16x16x32_bf16(Alo, BLf[j], acc[j], 0, 0, 0);
#pragma unroll
      for (int j = 0; j < 4; ++j)
        acc[j] = __builtin_amdgcn_mfma_f32_16x16x32_bf16(Alo, BHf[j], acc[j], 0, 0, 0);
#pragma unroll
      for (int j = 0; j < 4; ++j)
        acc[j] = __builtin_amdgcn_mfma_f32_16x16x32_bf16(Ahi, BLf[j], acc[j], 0, 0, 0);
#pragma unroll
      for (int j = 0; j < 4; ++j)
        acc[j] = __builtin_amdgcn_mfma_f32_16x16x32_bf16(Ahi, BHf[j], acc[j], 0, 0, 0);
    }
  }

  // ---- epilogue: transpose scores to token-major LDS (aliases smem) ----
  __syncthreads();
  float* Ls = (float*)smem;  // 64*68*4 = 17408 B <= 65536
#pragma unroll
  for (int j = 0; j < 4; ++j)
#pragma unroll
    for (int r = 0; r < 4; ++r)
      Ls[(16 * wave + 4 * lk + r) * LSTR + 16 * j + lr] = acc[j][r];
  __syncthreads();

  const float bv = bias[lane];
  for (int tt = 0; tt < 16; ++tt) {
    const int tl = wave * 16 + tt;
    const int t = row0 + tl;
    const float s = Ls[tl * LSTR + lane] + bv;

    float m = s;
#pragma unroll
    for (int off = 32; off >= 1; off >>= 1) m = fmaxf(m, __shfl_xor(m, off));
    const float e = expf(s - m);
    float sum = e;
#pragma unroll
    for (int off = 32; off >= 1; off >>= 1) sum += __shfl_xor(sum, off);
    const float p = e / sum;

    // top-9 on biased raw score, lowest-index tie-break (matches lax.top_k)
    float wsel = s;
    float rv = 0.f;
    int ri = 0;
    float prev = 0.f, mingap = 1e30f;
#pragma unroll
    for (int r = 0; r < 9; ++r) {
      float v = wsel;
      int ii = lane;
#pragma unroll
      for (int off = 32; off >= 1; off >>= 1) {
        const float ov = __shfl_xor(v, off);
        const int oi = __shfl_xor(ii, off);
        if (ov > v || (ov == v && oi < ii)) { v = ov; ii = oi; }
      }
      if (r > 0) mingap = fminf(mingap, prev - v);
      prev = v;
      const float pw = __shfl(p, ii);
      if (lane == r) { rv = pw; ri = ii; }
      if (lane == ii) wsel = -1e30f;
    }

    bool toC = false;
    if (mingap < TAU && cap > 0) {
      int pos = 0;
      if (lane == 0) pos = atomicAdd(cnt, 1);
      pos = __shfl(pos, 0);
      if (pos < cap) {
        if (lane == 0) list[pos] = t;
        toC = true;  // recompute kernel produces all outputs for this token
      }
    }
    if (!toC) {
      S[(size_t)t * NE + lane] = p;
      if (lane < K) {
        wout[(size_t)t * K + lane] = rv;
        iout[(size_t)t * K + lane] = (float)ri;
        atomicAdd(&hist_s[ri], 1);
      }
    }
  }
  __syncthreads();
  if (tid < NE) atomicAdd(&hist[tid], hist_s[tid]);
}

// -------- f64 finalize for one token (lanes 0..63) ---------------
__device__ __forceinline__ void finalize_token_f64(
    int t, int lane, double s, float* __restrict__ S, float* __restrict__ wout,
    float* __restrict__ iout, int* __restrict__ hist, int K) {
  double m = s;
#pragma unroll
  for (int off = 32; off >= 1; off >>= 1) m = fmax(m, __shfl_xor(m, off));
  const double ex = exp(s - m);
  double sum = ex;
#pragma unroll
  for (int off = 32; off >= 1; off >>= 1) sum += __shfl_xor(sum, off);
  const double p = ex / sum;
  S[(size_t)t * NE + lane] = (float)p;
  double wsel = s;
  double rv = 0.0;
  int ri = 0;
  for (int r = 0; r < K; ++r) {
    double v = wsel;
    int ii = lane;
#pragma unroll
    for (int off = 32; off >= 1; off >>= 1) {
      const double ov = __shfl_xor(v, off);
      const int oi = __shfl_xor(ii, off);
      if (ov > v || (ov == v && oi < ii)) { v = ov; ii = oi; }
    }
    const double pw = __shfl(p, ii);
    if (lane == r) { rv = pw; ri = ii; }
    if (lane == ii) wsel = -1e300;
  }
  if (lane < K) {
    wout[(size_t)t * K + lane] = (float)rv;
    iout[(size_t)t * K + lane] = (float)ri;
    atomicAdd(&hist[ri], 1);
  }
}

// ------- Kernel 2: f64 recompute, 1 token/block, grid 512 -------------------
__global__ __launch_bounds__(256) void recompute_f64(
    const float* __restrict__ X, const float* __restrict__ W,
    const float* __restrict__ bias, float* __restrict__ S,
    float* __restrict__ wout, float* __restrict__ iout,
    const int* __restrict__ cnt, const int* __restrict__ list,
    int* __restrict__ hist, int H, int K, int cap) {
  if (cap <= 0) return;
  __shared__ float4 xs[1024];  // one token row (16 KB)
  __shared__ double red[256];
  const int tid = threadIdx.x;
  const int n = min(*cnt, cap);
  const int H4 = H >> 2;
  for (int idx = blockIdx.x; idx < n; idx += gridDim.x) {
    const int t = list[idx];
    __syncthreads();  // xs reuse from previous iteration
    const float4* xg = reinterpret_cast<const float4*>(X + (size_t)t * H);
    for (int i = tid; i < H4; i += 256) xs[i] = xg[i];
    __syncthreads();
    const int e = tid & 63, sl = tid >> 6;
    const int seg = H4 >> 2;  // 256 float4 per slice
    const float4* wr =
        reinterpret_cast<const float4*>(W + (size_t)e * H) + (size_t)sl * seg;
    const float4* xr = &xs[sl * seg];
    double a0 = 0.0, a1 = 0.0;  // split accumulators (break f64 dep chain)
    for (int k = 0; k < seg; k += 2) {
      const float4 w0 = wr[k], w1 = wr[k + 1];
      const float4 v0 = xr[k], v1 = xr[k + 1];
      a0 = fma((double)v0.x, (double)w0.x, a0);
      a0 = fma((double)v0.y, (double)w0.y, a0);
      a0 = fma((double)v0.z, (double)w0.z, a0);
      a0 = fma((double)v0.w, (double)w0.w, a0);
      a1 = fma((double)v1.x, (double)w1.x, a1);
      a1 = fma((double)v1.y, (double)w1.y, a1);
      a1 = fma((double)v1.z, (double)w1.z, a1);
      a1 = fma((double)v1.w, (double)w1.w, a1);
    }
    red[tid] = a0 + a1;
    __syncthreads();
    if (tid < 64) {
      const double s =
          red[e] + red[64 + e] + red[128 + e] + red[192 + e] + (double)bias[e];
      finalize_token_f64(t, e, s, S, wout, iout, hist, K);
    }
  }
}

// ------------- Kernel 3: bias update from integer histogram -----------------
__global__ void bias_update(const int* __restrict__ hist,
                            const float* __restrict__ bias,
                            float* __restrict__ bout, float tpe) {
  const int e = threadIdx.x;
  const float d = (float)hist[e] - tpe;
  const float sg = (d > 0.f) ? 1.f : ((d < 0.f) ? -1.f : 0.f);
  bout[e] = bias[e] + 0.01f * sg;
}

extern "C" void kernel_launch(void* const* d_in, const int* in_sizes, int n_in,
                              void* d_out, int out_size, void* d_ws, size_t ws_size,
                              hipStream_t stream) {
  const float* x = (const float*)d_in[0];
  const float* w = (const float*)d_in[1];
  const float* bias = (const float*)d_in[2];
  const int E = in_sizes[2];                       // 64
  const int H = in_sizes[1] / E;                   // 4096
  const long long N = (long long)in_sizes[0] / H;  // 32768 tokens
  const int K = (int)(((long long)out_size - N * E - E) / (2 * N));  // 8

  float* S = (float*)d_out;            // [N][E] probs
  float* wout = S + (size_t)N * E;     // [N][K]
  float* iout = wout + (size_t)N * K;  // [N][K] indices as float
  float* bout = iout + (size_t)N * K;  // [E]

  // ws: [0,4) cnt | [256,512) hist | Whi @4KB (512KB) | Wlo | list after
  int* cnt = (int*)d_ws;
  int* hist = (int*)d_ws + 64;
  const size_t whalf = (size_t)E * H * sizeof(__bf16);  // 512 KB
  __bf16* Whi = (__bf16*)((char*)d_ws + 4096);
  __bf16* Wlo = (__bf16*)((char*)d_ws + 4096 + whalf);
  const size_t listoff = 4096 + 2 * whalf;
  int* list = (int*)((char*)d_ws + listoff);
  int cap = 0;
  if (ws_size > listoff + 65536)
    cap = (int)min((size_t)32768, (ws_size - listoff) / 4);

  zero512<<<dim3(1), dim3(128), 0, stream>>>((int*)d_ws);
  const int n8 = E * H / 8;
  wconvert<<<dim3((n8 + 255) / 256), 256, 0, stream>>>(w, Whi, Wlo, n8, H);
  gemm_fused<<<dim3((int)(N / 64)), 256, 0, stream>>>(
      x, Whi, Wlo, bias, S, wout, iout, cnt, hist, list, cap, H, K);
  recompute_f64<<<dim3(512), 256, 0, stream>>>(x, w, bias, S, wout, iout, cnt,
                                               list, hist, H, K, cap);
  bias_update<<<dim3(1), dim3(E), 0, stream>>>(hist, bias, bout,
                                               (float)((double)N * K / E));
}